// Round 2
// baseline (1538.618 us; speedup 1.0000x reference)
//
#include <hip/hip_runtime.h>

#define DEV static __device__ __forceinline__

DEV float bf2f(unsigned short u){ union{unsigned i; float f;} a; a.i=((unsigned)u)<<16; return a.f; }
DEV unsigned short f2bf(float f){ union{unsigned i; float f;} a; a.f=f; unsigned r=a.i+0x7fffu+((a.i>>16)&1u); return (unsigned short)(r>>16); }
DEV float2 bfu2f2(unsigned v){ union{unsigned i; float f;} lo,hi; lo.i=v<<16; hi.i=v&0xffff0000u; return make_float2(lo.f,hi.f); }

// ---------------- CSR build ----------------
__global__ __launch_bounds__(256) void hist_kernel(const int* __restrict__ dst, int* __restrict__ deg, int E){
  int i=blockIdx.x*256+threadIdx.x, st=gridDim.x*256;
  for(;i<E;i+=st) atomicAdd(&deg[dst[i]],1);
}

// offs = exclusive scan of deg; dinv = rsqrt(deg+1); bincur[b] = offs[128*b]
__global__ __launch_bounds__(1024) void scan_kernel(const int* __restrict__ deg, int* __restrict__ offs,
    int* __restrict__ bincur, float* __restrict__ dinv, int M){
  __shared__ int sums[1024];
  int t=threadIdx.x;
  int per=(M+1023)>>10;
  int s0=t*per, s1=min(s0+per,M);
  int s=0;
  for(int i=s0;i<s1;i++) s+=deg[i];
  sums[t]=s; __syncthreads();
  for(int o=1;o<1024;o<<=1){
    int v=(t>=o)?sums[t-o]:0;
    __syncthreads();
    if(t>=o) sums[t]+=v;
    __syncthreads();
  }
  int run=(t>0)?sums[t-1]:0;
  for(int i=s0;i<s1;i++){
    int d=deg[i];
    offs[i]=run;
    if((i&127)==0) bincur[i>>7]=run;
    dinv[i]=rsqrtf((float)(d+1));
    run+=d;
  }
}

// pass 1: scatter (src,dst) into per-bin windows of tmp (bins = 128-node ranges)
__global__ __launch_bounds__(256) void binscatter_kernel(const int* __restrict__ src, const int* __restrict__ dst,
    int* __restrict__ bincur, uint2* __restrict__ tmp, int E){
  int i=blockIdx.x*256+threadIdx.x, st=gridDim.x*256;
  for(;i<E;i+=st){
    int d=dst[i];
    int p=atomicAdd(&bincur[d>>7],1);
    tmp[p]=make_uint2((unsigned)src[i],(unsigned)d);
  }
}

// pass 2: one block per bin; LDS cursors -> dense writes into col's contiguous bin window
__global__ __launch_bounds__(256) void binsort_kernel(const uint2* __restrict__ tmp, const int* __restrict__ offs,
    int* __restrict__ col, int M, int E){
  __shared__ int cur[128];
  int b=blockIdx.x;
  int n0=b*128;
  int nend=min(n0+128,M);
  int t=threadIdx.x;
  if(t<nend-n0) cur[t]=offs[n0+t];
  __syncthreads();
  int e0=offs[n0];
  int e1=(nend<M)?offs[nend]:E;
  for(int i=e0+t;i<e1;i+=256){
    uint2 e=tmp[i];
    int p=atomicAdd(&cur[e.y&127],1);
    col[p]=(int)e.x;
  }
}

// ---------------- xs0 = dinv * x, padded to 22 cols ----------------
__global__ __launch_bounds__(256) void scale_kernel(const float* __restrict__ x, const float* __restrict__ dinv,
    float* __restrict__ xs, int M){
  int idx=blockIdx.x*256+threadIdx.x;
  if(idx>=M*11) return;
  int n=idx/11, l=idx-n*11;
  float dv=dinv[n];
  float a=x[(size_t)n*21+2*l];
  float b=(2*l+1<21)?x[(size_t)n*21+2*l+1]:0.f;
  ((float2*)xs)[(size_t)n*11+l]=make_float2(dv*a,dv*b);
}

// ---------------- aggregation: out[d] = dinv[d]*(in[d] + sum_{e:dst=d} in[src_e]) ----------------
// in is pre-scaled by dinv[src]. Each GROUP of lanes handles one node; lane -> 2 dims.
template<int GROUP,int F2,bool BR,bool INBF>
__global__ __launch_bounds__(256) void agg_kernel(const void* __restrict__ xs, const int* __restrict__ col,
    const int* __restrict__ offs, const int* __restrict__ deg, const float* __restrict__ dinv,
    const float* __restrict__ bias, float* __restrict__ out, int M){
  int gid=blockIdx.x*256+threadIdx.x;
  int node=gid/GROUP, lane=gid%GROUP;
  if(node>=M) return;
  bool act=lane<F2;
  const float2* basef=(const float2*)xs;
  const unsigned* baseb=(const unsigned*)xs;
  float ax=0.f, ay=0.f;
  if(act){
    if constexpr(INBF){ float2 v=bfu2f2(baseb[(size_t)node*F2+lane]); ax=v.x; ay=v.y; }
    else { float2 v=basef[(size_t)node*F2+lane]; ax=v.x; ay=v.y; }
  }
  int e0=offs[node], d=deg[node];
  int i=0;
  for(;i+4<=d;i+=4){
    int s0=col[e0+i], s1=col[e0+i+1], s2=col[e0+i+2], s3=col[e0+i+3];
    if(act){
      float2 v0,v1,v2,v3;
      if constexpr(INBF){
        v0=bfu2f2(baseb[(size_t)s0*F2+lane]);
        v1=bfu2f2(baseb[(size_t)s1*F2+lane]);
        v2=bfu2f2(baseb[(size_t)s2*F2+lane]);
        v3=bfu2f2(baseb[(size_t)s3*F2+lane]);
      } else {
        v0=basef[(size_t)s0*F2+lane];
        v1=basef[(size_t)s1*F2+lane];
        v2=basef[(size_t)s2*F2+lane];
        v3=basef[(size_t)s3*F2+lane];
      }
      ax+=(v0.x+v1.x)+(v2.x+v3.x);
      ay+=(v0.y+v1.y)+(v2.y+v3.y);
    }
  }
  for(;i<d;i++){
    int s=col[e0+i];
    if(act){
      float2 v;
      if constexpr(INBF) v=bfu2f2(baseb[(size_t)s*F2+lane]);
      else v=basef[(size_t)s*F2+lane];
      ax+=v.x; ay+=v.y;
    }
  }
  if(!act) return;
  float dv=dinv[node];
  ax*=dv; ay*=dv;
  if constexpr(BR){
    ax=fmaxf(ax+bias[2*lane],0.f);
    ay=fmaxf(ay+bias[2*lane+1],0.f);
  }
  ((float2*)out)[(size_t)node*F2+lane]=make_float2(ax,ay);
}

// ---------------- tiled GEMM: Out[M,N] = epilogue(X[M,K] @ W[RK,N]) ----------------
template<int K,int RK,int N,int NB,bool INBF,bool OUTBF,bool BR,bool DV>
__global__ __launch_bounds__(256) void gemm_kernel(const void* __restrict__ Xin, const float* __restrict__ W,
    const float* __restrict__ bias, const float* __restrict__ dinv, void* __restrict__ Out, int M){
  __shared__ float Wl[K*N];
  __shared__ float Xl[NB*K];
  int tid=threadIdx.x;
  for(int i=tid;i<K*N;i+=256){ int r=i/N; Wl[i]=(r<RK)?W[i]:0.f; }
  int nbase=blockIdx.x*NB;
  if constexpr(!INBF){
    const float* X=(const float*)Xin;
    for(int i=tid;i<NB*K;i+=256){ int r=i/K, c=i-r*K; int n=nbase+r; Xl[i]=(n<M)?X[(size_t)n*K+c]:0.f; }
  } else {
    const unsigned short* X=(const unsigned short*)Xin;
    for(int i=tid;i<NB*K;i+=256){ int r=i/K, c=i-r*K; int n=nbase+r; Xl[i]=(n<M)?bf2f(X[(size_t)n*K+c]):0.f; }
  }
  __syncthreads();
  constexpr int ROWS=NB/4;
  constexpr int NC=N/64;
  int lane=tid&63, wave=tid>>6;
  int rowbase=wave*ROWS;
  float acc[ROWS][NC];
  #pragma unroll
  for(int i=0;i<ROWS;i++)
    #pragma unroll
    for(int j=0;j<NC;j++) acc[i][j]=0.f;

  if constexpr((K&3)==0){
    for(int k=0;k<K;k+=4){
      float wv[4][NC];
      #pragma unroll
      for(int q=0;q<4;q++)
        #pragma unroll
        for(int j=0;j<NC;j++) wv[q][j]=Wl[(k+q)*N+j*64+lane];
      #pragma unroll
      for(int i=0;i<ROWS;i++){
        float4 xv=*(const float4*)&Xl[(rowbase+i)*K+k];
        #pragma unroll
        for(int j=0;j<NC;j++){
          acc[i][j]=fmaf(xv.x,wv[0][j],acc[i][j]);
          acc[i][j]=fmaf(xv.y,wv[1][j],acc[i][j]);
          acc[i][j]=fmaf(xv.z,wv[2][j],acc[i][j]);
          acc[i][j]=fmaf(xv.w,wv[3][j],acc[i][j]);
        }
      }
    }
  } else {
    for(int k=0;k<K;k++){
      float wv[NC];
      #pragma unroll
      for(int j=0;j<NC;j++) wv[j]=Wl[k*N+j*64+lane];
      #pragma unroll
      for(int i=0;i<ROWS;i++){
        float xv=Xl[(rowbase+i)*K+k];
        #pragma unroll
        for(int j=0;j<NC;j++) acc[i][j]=fmaf(xv,wv[j],acc[i][j]);
      }
    }
  }
  float bv[NC];
  if constexpr(BR){
    #pragma unroll
    for(int j=0;j<NC;j++) bv[j]=bias[j*64+lane];
  }
  #pragma unroll
  for(int i=0;i<ROWS;i++){
    int n=nbase+rowbase+i;
    if(n<M){
      float dv=1.f;
      if constexpr(DV) dv=dinv[n];
      #pragma unroll
      for(int j=0;j<NC;j++){
        float v=acc[i][j];
        if constexpr(BR) v=fmaxf(v+bv[j],0.f);
        if constexpr(DV) v*=dv;
        int c=j*64+lane;
        if constexpr(OUTBF) ((unsigned short*)Out)[(size_t)n*N+c]=f2bf(v);
        else ((float*)Out)[(size_t)n*N+c]=v;
      }
    }
  }
}

// ---------------- fused MLP head: out = (relu(h@Wl1+bl1))@Wl2 + bl2 ----------------
__global__ __launch_bounds__(256) void mlp_kernel(const float* __restrict__ h, const float* __restrict__ W1,
    const float* __restrict__ b1, const float* __restrict__ W2, const float* __restrict__ b2,
    float* __restrict__ out, int M){
  __shared__ float W1s[64*20];
  __shared__ float b1s[20];
  __shared__ float W2s[20];
  __shared__ float b2s;
  int tid=threadIdx.x;
  for(int i=tid;i<1280;i+=256) W1s[i]=W1[i];
  if(tid<20){ b1s[tid]=b1[tid]; W2s[tid]=W2[tid]; }
  if(tid==0) b2s=b2[0];
  __syncthreads();
  int n=blockIdx.x*256+tid;
  if(n>=M) return;
  float acc[20];
  #pragma unroll
  for(int j=0;j<20;j++) acc[j]=b1s[j];
  const float4* hp=(const float4*)(h+(size_t)n*64);
  for(int k4=0;k4<16;k4++){
    float4 hv=hp[k4];
    #pragma unroll
    for(int j=0;j<20;j++){
      acc[j]=fmaf(hv.x,W1s[(k4*4+0)*20+j],acc[j]);
      acc[j]=fmaf(hv.y,W1s[(k4*4+1)*20+j],acc[j]);
      acc[j]=fmaf(hv.z,W1s[(k4*4+2)*20+j],acc[j]);
      acc[j]=fmaf(hv.w,W1s[(k4*4+3)*20+j],acc[j]);
    }
  }
  float r=b2s;
  #pragma unroll
  for(int j=0;j<20;j++) r+=fmaxf(acc[j],0.f)*W2s[j];
  out[n]=r;
}

extern "C" void kernel_launch(void* const* d_in, const int* in_sizes, int n_in,
                              void* d_out, int out_size, void* d_ws, size_t ws_size,
                              hipStream_t stream){
  const float* x  =(const float*)d_in[0];
  const int*   ei =(const int*)  d_in[1];
  const float* W1 =(const float*)d_in[2];
  const float* b1 =(const float*)d_in[3];
  const float* W2 =(const float*)d_in[4];
  const float* b2 =(const float*)d_in[5];
  const float* W3 =(const float*)d_in[6];
  const float* b3 =(const float*)d_in[7];
  const float* Wl1=(const float*)d_in[8];
  const float* bl1=(const float*)d_in[9];
  const float* Wl2=(const float*)d_in[10];
  const float* bl2=(const float*)d_in[11];
  const int M=in_sizes[0]/21;
  const int E=in_sizes[1]/2;
  const int* srcp=ei;
  const int* dstp=ei+(size_t)E;
  const int NBINS=(M+127)>>7;

  char* ws=(char*)d_ws;
  size_t off=0;
  auto alloc=[&](size_t bytes)->void*{
    off=(off+255)&~(size_t)255;
    void* p=ws+off; off+=bytes; return p;
  };
  int*   deg   =(int*)  alloc((size_t)M*4);
  int*   offs  =(int*)  alloc((size_t)M*4);
  float* dinv  =(float*)alloc((size_t)M*4);
  int*   bincur=(int*)  alloc((size_t)NBINS*4);
  int*   col   =(int*)  alloc((size_t)E*4);
  // four reusable 256B-per-node slots
  float* A=(float*)alloc((size_t)M*256);   // (aliased: uint2 tmp[E])  xs0 f32[M,22]  -> h2 bf16[M,128]
  float* B=(float*)alloc((size_t)M*256);   // Y1  f32[M,22]  -> ts  bf16[M,64]
  float* C=(float*)alloc((size_t)M*256);   // xs1 f32[M,64]  -> h3  f32[M,64]
  float* D=(float*)alloc((size_t)M*256);   // Y2  f32[M,64]
  uint2* tmp=(uint2*)A;                    // E*8 bytes == M*256 bytes
  (void)ws_size;(void)n_in;(void)out_size;

  hipMemsetAsync(deg,0,(size_t)M*4,stream);
  hist_kernel<<<2048,256,0,stream>>>(dstp,deg,E);
  scan_kernel<<<1,1024,0,stream>>>(deg,offs,bincur,dinv,M);
  binscatter_kernel<<<2048,256,0,stream>>>(srcp,dstp,bincur,tmp,E);
  binsort_kernel<<<NBINS,256,0,stream>>>(tmp,offs,col,M,E);

  // layer 1: aggregate in 21-dim, then GEMM 21->64 (bias+relu+dinv into xs1)
  scale_kernel<<<(M*11+255)/256,256,0,stream>>>(x,dinv,A,M);
  agg_kernel<16,11,false,false><<<(M*16+255)/256,256,0,stream>>>(A,col,offs,deg,dinv,nullptr,B,M);
  gemm_kernel<22,21,64,64,false,false,true,true><<<(M+63)/64,256,0,stream>>>(B,W1,b1,dinv,C,M);
  // layer 2: aggregate in 64-dim (pre-GEMM), then GEMM 64->128 (bias+relu), h2 in bf16
  agg_kernel<32,32,false,false><<<(M*32+255)/256,256,0,stream>>>(C,col,offs,deg,dinv,nullptr,D,M);
  gemm_kernel<64,64,128,64,false,true,true,false><<<(M+63)/64,256,0,stream>>>(D,W2,b2,nullptr,A,M);
  // layer 3: GEMM 128->64 first (dinv into ts, bf16), then aggregate (bias+relu epilogue)
  gemm_kernel<128,128,64,32,true,true,false,true><<<(M+31)/32,256,0,stream>>>(A,W3,nullptr,dinv,B,M);
  agg_kernel<32,32,true,true><<<(M*32+255)/256,256,0,stream>>>(B,col,offs,deg,dinv,b3,C,M);
  // MLP head
  mlp_kernel<<<(M+255)/256,256,0,stream>>>(C,Wl1,bl1,Wl2,bl2,(float*)d_out,M);
}

// Round 3
// 520.767 us; speedup vs baseline: 2.9545x; 2.9545x over previous
//
#include <hip/hip_runtime.h>

#define DEV static __device__ __forceinline__

DEV float bf2f(unsigned short u){ union{unsigned i; float f;} a; a.i=((unsigned)u)<<16; return a.f; }
DEV unsigned short f2bf(float f){ union{unsigned i; float f;} a; a.f=f; unsigned r=a.i+0x7fffu+((a.i>>16)&1u); return (unsigned short)(r>>16); }
DEV float2 bfu2f2(unsigned v){ union{unsigned i; float f;} lo,hi; lo.i=v<<16; hi.i=v&0xffff0000u; return make_float2(lo.f,hi.f); }

// Coarse bins: 512 nodes each. Edge packed as src | (dst&511)<<23  (src < 2^23).
#define CB_SHIFT 9
#define CB_NODES 512
#define PK_SHIFT 23
#define PK_MASK  0x7fffffu

// ---------------- pass 0: coarse histogram (LDS-privatized) ----------------
__global__ __launch_bounds__(256) void coarsehist_kernel(const int* __restrict__ dst,
    int* __restrict__ bcnt, int E, int NB){
  __shared__ int h[256];
  int t=threadIdx.x;
  h[t]=0; __syncthreads();
  int i=blockIdx.x*256+t, st=gridDim.x*256;
  for(;i<E;i+=st) atomicAdd(&h[dst[i]>>CB_SHIFT],1);
  __syncthreads();
  if(t<NB && h[t]) atomicAdd(&bcnt[t],h[t]);
}

// ---------------- bin scan (1 block) ----------------
__global__ __launch_bounds__(256) void binscan_kernel(const int* __restrict__ bcnt,
    int* __restrict__ binoffs, int* __restrict__ bincur, int NB, int E){
  __shared__ int s[256];
  int t=threadIdx.x;
  int v=(t<NB)?bcnt[t]:0;
  s[t]=v; __syncthreads();
  for(int o=1;o<256;o<<=1){
    int u=(t>=o)?s[t-o]:0;
    __syncthreads();
    if(t>=o) s[t]+=u;
    __syncthreads();
  }
  int ex=s[t]-v;
  if(t<NB){ binoffs[t]=ex; bincur[t]=ex; }
  if(t==0) binoffs[NB]=E;
}

// ---------------- pass 1: chunked ranked scatter into coarse-bin windows ----------------
__global__ __launch_bounds__(256) void chunkscatter_kernel(const int* __restrict__ src,
    const int* __restrict__ dst, int* __restrict__ bincur, unsigned* __restrict__ tmp,
    int E, int NB, int C){
  __shared__ int lcnt[256];
  __shared__ int lbase[256];
  int t=threadIdx.x;
  lcnt[t]=0; __syncthreads();
  int e0=blockIdx.x*C, e1=min(e0+C,E);
  for(int i=e0+t;i<e1;i+=256) atomicAdd(&lcnt[dst[i]>>CB_SHIFT],1);
  __syncthreads();
  if(t<NB){ int c=lcnt[t]; lbase[t]=c?atomicAdd(&bincur[t],c):0; }
  __syncthreads();
  lcnt[t]=0; __syncthreads();
  for(int i=e0+t;i<e1;i+=256){
    int d=dst[i];
    int b=d>>CB_SHIFT;
    int r=atomicAdd(&lcnt[b],1);
    tmp[lbase[b]+r]=(unsigned)src[i]|((unsigned)(d&(CB_NODES-1))<<PK_SHIFT);
  }
}

// ---------------- pass 2: per-bin node sort; emits offs/deg/dinv/col ----------------
__global__ __launch_bounds__(256) void binsort_kernel(const unsigned* __restrict__ tmp,
    const int* __restrict__ binoffs, int* __restrict__ offs, int* __restrict__ deg,
    float* __restrict__ dinv, int* __restrict__ col, int M){
  __shared__ int cnt[CB_NODES];
  __shared__ int cur[CB_NODES];
  __shared__ int ssum[256];
  int b=blockIdx.x, t=threadIdx.x;
  int n0=b*CB_NODES;
  int e0=binoffs[b], e1=binoffs[b+1];
  cnt[2*t]=0; cnt[2*t+1]=0;
  __syncthreads();
  for(int i=e0+t;i<e1;i+=256) atomicAdd(&cnt[tmp[i]>>PK_SHIFT],1);
  __syncthreads();
  int a=cnt[2*t], c=cnt[2*t+1];
  ssum[t]=a+c; __syncthreads();
  for(int o=1;o<256;o<<=1){
    int u=(t>=o)?ssum[t-o]:0;
    __syncthreads();
    if(t>=o) ssum[t]+=u;
    __syncthreads();
  }
  int ex=e0+ssum[t]-(a+c);
  cur[2*t]=ex; cur[2*t+1]=ex+a;
  int na=n0+2*t, nb=n0+2*t+1;
  if(na<M){ offs[na]=ex;   deg[na]=a; dinv[na]=rsqrtf((float)(a+1)); }
  if(nb<M){ offs[nb]=ex+a; deg[nb]=c; dinv[nb]=rsqrtf((float)(c+1)); }
  __syncthreads();
  for(int i=e0+t;i<e1;i+=256){
    unsigned p=tmp[i];
    int pos=atomicAdd(&cur[p>>PK_SHIFT],1);
    col[pos]=(int)(p&PK_MASK);
  }
}

// ---------------- xs0 = dinv * x, padded to 22 cols ----------------
__global__ __launch_bounds__(256) void scale_kernel(const float* __restrict__ x, const float* __restrict__ dinv,
    float* __restrict__ xs, int M){
  int idx=blockIdx.x*256+threadIdx.x;
  if(idx>=M*11) return;
  int n=idx/11, l=idx-n*11;
  float dv=dinv[n];
  float a=x[(size_t)n*21+2*l];
  float b=(2*l+1<21)?x[(size_t)n*21+2*l+1]:0.f;
  ((float2*)xs)[(size_t)n*11+l]=make_float2(dv*a,dv*b);
}

// ---------------- aggregation: out[d] = dinv[d]*(in[d] + sum_{e:dst=d} in[src_e]) ----------------
template<int GROUP,int F2,bool BR,bool INBF>
__global__ __launch_bounds__(256) void agg_kernel(const void* __restrict__ xs, const int* __restrict__ col,
    const int* __restrict__ offs, const int* __restrict__ deg, const float* __restrict__ dinv,
    const float* __restrict__ bias, float* __restrict__ out, int M){
  int gid=blockIdx.x*256+threadIdx.x;
  int node=gid/GROUP, lane=gid%GROUP;
  if(node>=M) return;
  bool act=lane<F2;
  const float2* basef=(const float2*)xs;
  const unsigned* baseb=(const unsigned*)xs;
  float ax=0.f, ay=0.f;
  if(act){
    if constexpr(INBF){ float2 v=bfu2f2(baseb[(size_t)node*F2+lane]); ax=v.x; ay=v.y; }
    else { float2 v=basef[(size_t)node*F2+lane]; ax=v.x; ay=v.y; }
  }
  int e0=offs[node], d=deg[node];
  int i=0;
  for(;i+4<=d;i+=4){
    int s0=col[e0+i], s1=col[e0+i+1], s2=col[e0+i+2], s3=col[e0+i+3];
    if(act){
      float2 v0,v1,v2,v3;
      if constexpr(INBF){
        v0=bfu2f2(baseb[(size_t)s0*F2+lane]);
        v1=bfu2f2(baseb[(size_t)s1*F2+lane]);
        v2=bfu2f2(baseb[(size_t)s2*F2+lane]);
        v3=bfu2f2(baseb[(size_t)s3*F2+lane]);
      } else {
        v0=basef[(size_t)s0*F2+lane];
        v1=basef[(size_t)s1*F2+lane];
        v2=basef[(size_t)s2*F2+lane];
        v3=basef[(size_t)s3*F2+lane];
      }
      ax+=(v0.x+v1.x)+(v2.x+v3.x);
      ay+=(v0.y+v1.y)+(v2.y+v3.y);
    }
  }
  for(;i<d;i++){
    int s=col[e0+i];
    if(act){
      float2 v;
      if constexpr(INBF) v=bfu2f2(baseb[(size_t)s*F2+lane]);
      else v=basef[(size_t)s*F2+lane];
      ax+=v.x; ay+=v.y;
    }
  }
  if(!act) return;
  float dv=dinv[node];
  ax*=dv; ay*=dv;
  if constexpr(BR){
    ax=fmaxf(ax+bias[2*lane],0.f);
    ay=fmaxf(ay+bias[2*lane+1],0.f);
  }
  ((float2*)out)[(size_t)node*F2+lane]=make_float2(ax,ay);
}

// ---------------- tiled GEMM: Out[M,N] = epilogue(X[M,K] @ W[RK,N]) ----------------
template<int K,int RK,int N,int NB,bool INBF,bool OUTBF,bool BR,bool DV>
__global__ __launch_bounds__(256) void gemm_kernel(const void* __restrict__ Xin, const float* __restrict__ W,
    const float* __restrict__ bias, const float* __restrict__ dinv, void* __restrict__ Out, int M){
  __shared__ float Wl[K*N];
  __shared__ float Xl[NB*K];
  int tid=threadIdx.x;
  for(int i=tid;i<K*N;i+=256){ int r=i/N; Wl[i]=(r<RK)?W[i]:0.f; }
  int nbase=blockIdx.x*NB;
  if constexpr(!INBF){
    const float* X=(const float*)Xin;
    for(int i=tid;i<NB*K;i+=256){ int r=i/K, c=i-r*K; int n=nbase+r; Xl[i]=(n<M)?X[(size_t)n*K+c]:0.f; }
  } else {
    const unsigned short* X=(const unsigned short*)Xin;
    for(int i=tid;i<NB*K;i+=256){ int r=i/K, c=i-r*K; int n=nbase+r; Xl[i]=(n<M)?bf2f(X[(size_t)n*K+c]):0.f; }
  }
  __syncthreads();
  constexpr int ROWS=NB/4;
  constexpr int NC=N/64;
  int lane=tid&63, wave=tid>>6;
  int rowbase=wave*ROWS;
  float acc[ROWS][NC];
  #pragma unroll
  for(int i=0;i<ROWS;i++)
    #pragma unroll
    for(int j=0;j<NC;j++) acc[i][j]=0.f;

  if constexpr((K&3)==0){
    for(int k=0;k<K;k+=4){
      float wv[4][NC];
      #pragma unroll
      for(int q=0;q<4;q++)
        #pragma unroll
        for(int j=0;j<NC;j++) wv[q][j]=Wl[(k+q)*N+j*64+lane];
      #pragma unroll
      for(int i=0;i<ROWS;i++){
        float4 xv=*(const float4*)&Xl[(rowbase+i)*K+k];
        #pragma unroll
        for(int j=0;j<NC;j++){
          acc[i][j]=fmaf(xv.x,wv[0][j],acc[i][j]);
          acc[i][j]=fmaf(xv.y,wv[1][j],acc[i][j]);
          acc[i][j]=fmaf(xv.z,wv[2][j],acc[i][j]);
          acc[i][j]=fmaf(xv.w,wv[3][j],acc[i][j]);
        }
      }
    }
  } else {
    for(int k=0;k<K;k++){
      float wv[NC];
      #pragma unroll
      for(int j=0;j<NC;j++) wv[j]=Wl[k*N+j*64+lane];
      #pragma unroll
      for(int i=0;i<ROWS;i++){
        float xv=Xl[(rowbase+i)*K+k];
        #pragma unroll
        for(int j=0;j<NC;j++) acc[i][j]=fmaf(xv,wv[j],acc[i][j]);
      }
    }
  }
  float bv[NC];
  if constexpr(BR){
    #pragma unroll
    for(int j=0;j<NC;j++) bv[j]=bias[j*64+lane];
  }
  #pragma unroll
  for(int i=0;i<ROWS;i++){
    int n=nbase+rowbase+i;
    if(n<M){
      float dv=1.f;
      if constexpr(DV) dv=dinv[n];
      #pragma unroll
      for(int j=0;j<NC;j++){
        float v=acc[i][j];
        if constexpr(BR) v=fmaxf(v+bv[j],0.f);
        if constexpr(DV) v*=dv;
        int c=j*64+lane;
        if constexpr(OUTBF) ((unsigned short*)Out)[(size_t)n*N+c]=f2bf(v);
        else ((float*)Out)[(size_t)n*N+c]=v;
      }
    }
  }
}

// ---------------- fused MLP head: out = (relu(h@Wl1+bl1))@Wl2 + bl2 ----------------
__global__ __launch_bounds__(256) void mlp_kernel(const float* __restrict__ h, const float* __restrict__ W1,
    const float* __restrict__ b1, const float* __restrict__ W2, const float* __restrict__ b2,
    float* __restrict__ out, int M){
  __shared__ float W1s[64*20];
  __shared__ float b1s[20];
  __shared__ float W2s[20];
  __shared__ float b2s;
  int tid=threadIdx.x;
  for(int i=tid;i<1280;i+=256) W1s[i]=W1[i];
  if(tid<20){ b1s[tid]=b1[tid]; W2s[tid]=W2[tid]; }
  if(tid==0) b2s=b2[0];
  __syncthreads();
  int n=blockIdx.x*256+tid;
  if(n>=M) return;
  float acc[20];
  #pragma unroll
  for(int j=0;j<20;j++) acc[j]=b1s[j];
  const float4* hp=(const float4*)(h+(size_t)n*64);
  for(int k4=0;k4<16;k4++){
    float4 hv=hp[k4];
    #pragma unroll
    for(int j=0;j<20;j++){
      acc[j]=fmaf(hv.x,W1s[(k4*4+0)*20+j],acc[j]);
      acc[j]=fmaf(hv.y,W1s[(k4*4+1)*20+j],acc[j]);
      acc[j]=fmaf(hv.z,W1s[(k4*4+2)*20+j],acc[j]);
      acc[j]=fmaf(hv.w,W1s[(k4*4+3)*20+j],acc[j]);
    }
  }
  float r=b2s;
  #pragma unroll
  for(int j=0;j<20;j++) r+=fmaxf(acc[j],0.f)*W2s[j];
  out[n]=r;
}

extern "C" void kernel_launch(void* const* d_in, const int* in_sizes, int n_in,
                              void* d_out, int out_size, void* d_ws, size_t ws_size,
                              hipStream_t stream){
  const float* x  =(const float*)d_in[0];
  const int*   ei =(const int*)  d_in[1];
  const float* W1 =(const float*)d_in[2];
  const float* b1 =(const float*)d_in[3];
  const float* W2 =(const float*)d_in[4];
  const float* b2 =(const float*)d_in[5];
  const float* W3 =(const float*)d_in[6];
  const float* b3 =(const float*)d_in[7];
  const float* Wl1=(const float*)d_in[8];
  const float* bl1=(const float*)d_in[9];
  const float* Wl2=(const float*)d_in[10];
  const float* bl2=(const float*)d_in[11];
  const int M=in_sizes[0]/21;
  const int E=in_sizes[1]/2;
  const int* srcp=ei;
  const int* dstp=ei+(size_t)E;
  const int NB=(M+CB_NODES-1)/CB_NODES;   // coarse bins (<=256 for M<=131072)
  const int CHUNK=4096;

  char* ws=(char*)d_ws;
  size_t off=0;
  auto alloc=[&](size_t bytes)->void*{
    off=(off+255)&~(size_t)255;
    void* p=ws+off; off+=bytes; return p;
  };
  int*   offs   =(int*)  alloc((size_t)M*4);
  int*   deg    =(int*)  alloc((size_t)M*4);
  float* dinv   =(float*)alloc((size_t)M*4);
  int*   bcnt   =(int*)  alloc(256*4);
  int*   binoffs=(int*)  alloc(257*4);
  int*   bincur =(int*)  alloc(256*4);
  int*   col    =(int*)  alloc((size_t)E*4);
  // four reusable 256B-per-node slots
  float* A=(float*)alloc((size_t)M*256);   // (aliased: uint tmp[E])  xs0 f32[M,22]  -> h2 bf16[M,128]
  float* B=(float*)alloc((size_t)M*256);   // Y1  f32[M,22]  -> ts  bf16[M,64]
  float* C=(float*)alloc((size_t)M*256);   // xs1 f32[M,64]  -> h3  f32[M,64]
  float* D=(float*)alloc((size_t)M*256);   // Y2  f32[M,64]
  unsigned* tmp=(unsigned*)A;              // E*4 bytes <= M*256 bytes
  (void)ws_size;(void)n_in;(void)out_size;

  hipMemsetAsync(bcnt,0,256*4,stream);
  coarsehist_kernel<<<512,256,0,stream>>>(dstp,bcnt,E,NB);
  binscan_kernel<<<1,256,0,stream>>>(bcnt,binoffs,bincur,NB,E);
  chunkscatter_kernel<<<(E+CHUNK-1)/CHUNK,256,0,stream>>>(srcp,dstp,bincur,tmp,E,NB,CHUNK);
  binsort_kernel<<<NB,256,0,stream>>>(tmp,binoffs,offs,deg,dinv,col,M);

  // layer 1: aggregate in 21-dim, then GEMM 21->64 (bias+relu+dinv into xs1)
  scale_kernel<<<(M*11+255)/256,256,0,stream>>>(x,dinv,A,M);
  agg_kernel<16,11,false,false><<<(M*16+255)/256,256,0,stream>>>(A,col,offs,deg,dinv,nullptr,B,M);
  gemm_kernel<22,21,64,64,false,false,true,true><<<(M+63)/64,256,0,stream>>>(B,W1,b1,dinv,C,M);
  // layer 2: aggregate in 64-dim (pre-GEMM), then GEMM 64->128 (bias+relu), h2 in bf16
  agg_kernel<32,32,false,false><<<(M*32+255)/256,256,0,stream>>>(C,col,offs,deg,dinv,nullptr,D,M);
  gemm_kernel<64,64,128,64,false,true,true,false><<<(M+63)/64,256,0,stream>>>(D,W2,b2,nullptr,A,M);
  // layer 3: GEMM 128->64 first (dinv into ts, bf16), then aggregate (bias+relu epilogue)
  gemm_kernel<128,128,64,32,true,true,false,true><<<(M+31)/32,256,0,stream>>>(A,W3,nullptr,dinv,B,M);
  agg_kernel<32,32,true,true><<<(M*32+255)/256,256,0,stream>>>(B,col,offs,deg,dinv,b3,C,M);
  // MLP head
  mlp_kernel<<<(M+255)/256,256,0,stream>>>(C,Wl1,bl1,Wl2,bl2,(float*)d_out,M);
}

// Round 4
// 477.849 us; speedup vs baseline: 3.2199x; 1.0898x over previous
//
#include <hip/hip_runtime.h>

#define DEV static __device__ __forceinline__

DEV float bf2f(unsigned short u){ union{unsigned i; float f;} a; a.i=((unsigned)u)<<16; return a.f; }
DEV unsigned short f2bf(float f){ union{unsigned i; float f;} a; a.f=f; unsigned r=a.i+0x7fffu+((a.i>>16)&1u); return (unsigned short)(r>>16); }
DEV float2 bfu2f2(unsigned v){ union{unsigned i; float f;} lo,hi; lo.i=v<<16; hi.i=v&0xffff0000u; return make_float2(lo.f,hi.f); }

// Coarse bins: 512 nodes each. Edge packed as src | (dst&511)<<23  (src < 2^23).
#define CB_SHIFT 9
#define CB_NODES 512
#define PK_SHIFT 23
#define PK_MASK  0x7fffffu

// ---------------- pass 0: coarse histogram (LDS-privatized) ----------------
__global__ __launch_bounds__(256) void coarsehist_kernel(const int* __restrict__ dst,
    int* __restrict__ bcnt, int E, int NB){
  __shared__ int h[256];
  int t=threadIdx.x;
  h[t]=0; __syncthreads();
  int i=blockIdx.x*256+t, st=gridDim.x*256;
  for(;i<E;i+=st) atomicAdd(&h[dst[i]>>CB_SHIFT],1);
  __syncthreads();
  if(t<NB && h[t]) atomicAdd(&bcnt[t],h[t]);
}

// ---------------- bin scan (1 block) ----------------
__global__ __launch_bounds__(256) void binscan_kernel(const int* __restrict__ bcnt,
    int* __restrict__ binoffs, int* __restrict__ bincur, int NB, int E){
  __shared__ int s[256];
  int t=threadIdx.x;
  int v=(t<NB)?bcnt[t]:0;
  s[t]=v; __syncthreads();
  for(int o=1;o<256;o<<=1){
    int u=(t>=o)?s[t-o]:0;
    __syncthreads();
    if(t>=o) s[t]+=u;
    __syncthreads();
  }
  int ex=s[t]-v;
  if(t<NB){ binoffs[t]=ex; bincur[t]=ex; }
  if(t==0) binoffs[NB]=E;
}

// ---------------- pass 1: chunked ranked scatter into coarse-bin windows ----------------
__global__ __launch_bounds__(256) void chunkscatter_kernel(const int* __restrict__ src,
    const int* __restrict__ dst, int* __restrict__ bincur, unsigned* __restrict__ tmp,
    int E, int NB, int C){
  __shared__ int lcnt[256];
  __shared__ int lbase[256];
  int t=threadIdx.x;
  lcnt[t]=0; __syncthreads();
  int e0=blockIdx.x*C, e1=min(e0+C,E);
  for(int i=e0+t;i<e1;i+=256) atomicAdd(&lcnt[dst[i]>>CB_SHIFT],1);
  __syncthreads();
  if(t<NB){ int c=lcnt[t]; lbase[t]=c?atomicAdd(&bincur[t],c):0; }
  __syncthreads();
  lcnt[t]=0; __syncthreads();
  for(int i=e0+t;i<e1;i+=256){
    int d=dst[i];
    int b=d>>CB_SHIFT;
    int r=atomicAdd(&lcnt[b],1);
    tmp[lbase[b]+r]=(unsigned)src[i]|((unsigned)(d&(CB_NODES-1))<<PK_SHIFT);
  }
}

// ---------------- pass 2: per-bin node sort; emits offs/deg/dinv/col ----------------
__global__ __launch_bounds__(256) void binsort_kernel(const unsigned* __restrict__ tmp,
    const int* __restrict__ binoffs, int* __restrict__ offs, int* __restrict__ deg,
    float* __restrict__ dinv, int* __restrict__ col, int M){
  __shared__ int cnt[CB_NODES];
  __shared__ int cur[CB_NODES];
  __shared__ int ssum[256];
  int b=blockIdx.x, t=threadIdx.x;
  int n0=b*CB_NODES;
  int e0=binoffs[b], e1=binoffs[b+1];
  cnt[2*t]=0; cnt[2*t+1]=0;
  __syncthreads();
  for(int i=e0+t;i<e1;i+=256) atomicAdd(&cnt[tmp[i]>>PK_SHIFT],1);
  __syncthreads();
  int a=cnt[2*t], c=cnt[2*t+1];
  ssum[t]=a+c; __syncthreads();
  for(int o=1;o<256;o<<=1){
    int u=(t>=o)?ssum[t-o]:0;
    __syncthreads();
    if(t>=o) ssum[t]+=u;
    __syncthreads();
  }
  int ex=e0+ssum[t]-(a+c);
  cur[2*t]=ex; cur[2*t+1]=ex+a;
  int na=n0+2*t, nb=n0+2*t+1;
  if(na<M){ offs[na]=ex;   deg[na]=a; dinv[na]=rsqrtf((float)(a+1)); }
  if(nb<M){ offs[nb]=ex+a; deg[nb]=c; dinv[nb]=rsqrtf((float)(c+1)); }
  __syncthreads();
  for(int i=e0+t;i<e1;i+=256){
    unsigned p=tmp[i];
    int pos=atomicAdd(&cur[p>>PK_SHIFT],1);
    col[pos]=(int)(p&PK_MASK);
  }
}

// ---------------- xs0 = dinv * x, padded to 22 cols ----------------
__global__ __launch_bounds__(256) void scale_kernel(const float* __restrict__ x, const float* __restrict__ dinv,
    float* __restrict__ xs, int M){
  int idx=blockIdx.x*256+threadIdx.x;
  if(idx>=M*11) return;
  int n=idx/11, l=idx-n*11;
  float dv=dinv[n];
  float a=x[(size_t)n*21+2*l];
  float b=(2*l+1<21)?x[(size_t)n*21+2*l+1]:0.f;
  ((float2*)xs)[(size_t)n*11+l]=make_float2(dv*a,dv*b);
}

// ---------------- aggregation: out[d] = dinv[d]*(in[d] + sum_{e:dst=d} in[src_e]) ----------------
template<int GROUP,int F2,bool BR,bool INBF>
__global__ __launch_bounds__(256) void agg_kernel(const void* __restrict__ xs, const int* __restrict__ col,
    const int* __restrict__ offs, const int* __restrict__ deg, const float* __restrict__ dinv,
    const float* __restrict__ bias, float* __restrict__ out, int M){
  int gid=blockIdx.x*256+threadIdx.x;
  int node=gid/GROUP, lane=gid%GROUP;
  if(node>=M) return;
  bool act=lane<F2;
  const float2* basef=(const float2*)xs;
  const unsigned* baseb=(const unsigned*)xs;
  float ax=0.f, ay=0.f;
  if(act){
    if constexpr(INBF){ float2 v=bfu2f2(baseb[(size_t)node*F2+lane]); ax=v.x; ay=v.y; }
    else { float2 v=basef[(size_t)node*F2+lane]; ax=v.x; ay=v.y; }
  }
  int e0=offs[node], d=deg[node];
  int i=0;
  for(;i+4<=d;i+=4){
    int s0=col[e0+i], s1=col[e0+i+1], s2=col[e0+i+2], s3=col[e0+i+3];
    if(act){
      float2 v0,v1,v2,v3;
      if constexpr(INBF){
        v0=bfu2f2(baseb[(size_t)s0*F2+lane]);
        v1=bfu2f2(baseb[(size_t)s1*F2+lane]);
        v2=bfu2f2(baseb[(size_t)s2*F2+lane]);
        v3=bfu2f2(baseb[(size_t)s3*F2+lane]);
      } else {
        v0=basef[(size_t)s0*F2+lane];
        v1=basef[(size_t)s1*F2+lane];
        v2=basef[(size_t)s2*F2+lane];
        v3=basef[(size_t)s3*F2+lane];
      }
      ax+=(v0.x+v1.x)+(v2.x+v3.x);
      ay+=(v0.y+v1.y)+(v2.y+v3.y);
    }
  }
  for(;i<d;i++){
    int s=col[e0+i];
    if(act){
      float2 v;
      if constexpr(INBF) v=bfu2f2(baseb[(size_t)s*F2+lane]);
      else v=basef[(size_t)s*F2+lane];
      ax+=v.x; ay+=v.y;
    }
  }
  if(!act) return;
  float dv=dinv[node];
  ax*=dv; ay*=dv;
  if constexpr(BR){
    ax=fmaxf(ax+bias[2*lane],0.f);
    ay=fmaxf(ay+bias[2*lane+1],0.f);
  }
  ((float2*)out)[(size_t)node*F2+lane]=make_float2(ax,ay);
}

// ---------------- tiled GEMM: Out[M,N] = epilogue(X[M,K] @ W[RK,N]) ----------------
template<int K,int RK,int N,int NB,bool INBF,bool OUTBF,bool BR,bool DV>
__global__ __launch_bounds__(256) void gemm_kernel(const void* __restrict__ Xin, const float* __restrict__ W,
    const float* __restrict__ bias, const float* __restrict__ dinv, void* __restrict__ Out, int M){
  __shared__ float Wl[K*N];
  __shared__ float Xl[NB*K];
  int tid=threadIdx.x;
  for(int i=tid;i<K*N;i+=256){ int r=i/N; Wl[i]=(r<RK)?W[i]:0.f; }
  int nbase=blockIdx.x*NB;
  if constexpr(!INBF){
    const float* X=(const float*)Xin;
    for(int i=tid;i<NB*K;i+=256){ int r=i/K, c=i-r*K; int n=nbase+r; Xl[i]=(n<M)?X[(size_t)n*K+c]:0.f; }
  } else {
    const unsigned short* X=(const unsigned short*)Xin;
    for(int i=tid;i<NB*K;i+=256){ int r=i/K, c=i-r*K; int n=nbase+r; Xl[i]=(n<M)?bf2f(X[(size_t)n*K+c]):0.f; }
  }
  __syncthreads();
  constexpr int ROWS=NB/4;
  constexpr int NC=N/64;
  int lane=tid&63, wave=tid>>6;
  int rowbase=wave*ROWS;
  float acc[ROWS][NC];
  #pragma unroll
  for(int i=0;i<ROWS;i++)
    #pragma unroll
    for(int j=0;j<NC;j++) acc[i][j]=0.f;

  if constexpr((K&3)==0){
    for(int k=0;k<K;k+=4){
      float wv[4][NC];
      #pragma unroll
      for(int q=0;q<4;q++)
        #pragma unroll
        for(int j=0;j<NC;j++) wv[q][j]=Wl[(k+q)*N+j*64+lane];
      #pragma unroll
      for(int i=0;i<ROWS;i++){
        float4 xv=*(const float4*)&Xl[(rowbase+i)*K+k];
        #pragma unroll
        for(int j=0;j<NC;j++){
          acc[i][j]=fmaf(xv.x,wv[0][j],acc[i][j]);
          acc[i][j]=fmaf(xv.y,wv[1][j],acc[i][j]);
          acc[i][j]=fmaf(xv.z,wv[2][j],acc[i][j]);
          acc[i][j]=fmaf(xv.w,wv[3][j],acc[i][j]);
        }
      }
    }
  } else {
    for(int k=0;k<K;k++){
      float wv[NC];
      #pragma unroll
      for(int j=0;j<NC;j++) wv[j]=Wl[k*N+j*64+lane];
      #pragma unroll
      for(int i=0;i<ROWS;i++){
        float xv=Xl[(rowbase+i)*K+k];
        #pragma unroll
        for(int j=0;j<NC;j++) acc[i][j]=fmaf(xv,wv[j],acc[i][j]);
      }
    }
  }
  float bv[NC];
  if constexpr(BR){
    #pragma unroll
    for(int j=0;j<NC;j++) bv[j]=bias[j*64+lane];
  }
  #pragma unroll
  for(int i=0;i<ROWS;i++){
    int n=nbase+rowbase+i;
    if(n<M){
      float dv=1.f;
      if constexpr(DV) dv=dinv[n];
      #pragma unroll
      for(int j=0;j<NC;j++){
        float v=acc[i][j];
        if constexpr(BR) v=fmaxf(v+bv[j],0.f);
        if constexpr(DV) v*=dv;
        int c=j*64+lane;
        if constexpr(OUTBF) ((unsigned short*)Out)[(size_t)n*N+c]=f2bf(v);
        else ((float*)Out)[(size_t)n*N+c]=v;
      }
    }
  }
}

// ---------------- fused MLP head: out = (relu(h@Wl1+bl1))@Wl2 + bl2 ----------------
__global__ __launch_bounds__(256) void mlp_kernel(const float* __restrict__ h, const float* __restrict__ W1,
    const float* __restrict__ b1, const float* __restrict__ W2, const float* __restrict__ b2,
    float* __restrict__ out, int M){
  __shared__ float W1s[64*20];
  __shared__ float b1s[20];
  __shared__ float W2s[20];
  __shared__ float b2s;
  int tid=threadIdx.x;
  for(int i=tid;i<1280;i+=256) W1s[i]=W1[i];
  if(tid<20){ b1s[tid]=b1[tid]; W2s[tid]=W2[tid]; }
  if(tid==0) b2s=b2[0];
  __syncthreads();
  int n=blockIdx.x*256+tid;
  if(n>=M) return;
  float acc[20];
  #pragma unroll
  for(int j=0;j<20;j++) acc[j]=b1s[j];
  const float4* hp=(const float4*)(h+(size_t)n*64);
  for(int k4=0;k4<16;k4++){
    float4 hv=hp[k4];
    #pragma unroll
    for(int j=0;j<20;j++){
      acc[j]=fmaf(hv.x,W1s[(k4*4+0)*20+j],acc[j]);
      acc[j]=fmaf(hv.y,W1s[(k4*4+1)*20+j],acc[j]);
      acc[j]=fmaf(hv.z,W1s[(k4*4+2)*20+j],acc[j]);
      acc[j]=fmaf(hv.w,W1s[(k4*4+3)*20+j],acc[j]);
    }
  }
  float r=b2s;
  #pragma unroll
  for(int j=0;j<20;j++) r+=fmaxf(acc[j],0.f)*W2s[j];
  out[n]=r;
}

extern "C" void kernel_launch(void* const* d_in, const int* in_sizes, int n_in,
                              void* d_out, int out_size, void* d_ws, size_t ws_size,
                              hipStream_t stream){
  const float* x  =(const float*)d_in[0];
  const int*   ei =(const int*)  d_in[1];
  const float* W1 =(const float*)d_in[2];
  const float* b1 =(const float*)d_in[3];
  const float* W2 =(const float*)d_in[4];
  const float* b2 =(const float*)d_in[5];
  const float* W3 =(const float*)d_in[6];
  const float* b3 =(const float*)d_in[7];
  const float* Wl1=(const float*)d_in[8];
  const float* bl1=(const float*)d_in[9];
  const float* Wl2=(const float*)d_in[10];
  const float* bl2=(const float*)d_in[11];
  const int M=in_sizes[0]/21;
  const int E=in_sizes[1]/2;
  const int* srcp=ei;
  const int* dstp=ei+(size_t)E;
  const int NB=(M+CB_NODES-1)/CB_NODES;   // coarse bins (<=256 for M<=131072)
  const int CHUNK=4096;

  char* ws=(char*)d_ws;
  size_t off=0;
  auto alloc=[&](size_t bytes)->void*{
    off=(off+255)&~(size_t)255;
    void* p=ws+off; off+=bytes; return p;
  };
  int*   offs   =(int*)  alloc((size_t)M*4);
  int*   deg    =(int*)  alloc((size_t)M*4);
  float* dinv   =(float*)alloc((size_t)M*4);
  int*   bcnt   =(int*)  alloc(256*4);
  int*   binoffs=(int*)  alloc(257*4);
  int*   bincur =(int*)  alloc(256*4);
  int*   col    =(int*)  alloc((size_t)E*4);
  // four reusable 256B-per-node slots
  float* A=(float*)alloc((size_t)M*256);   // (aliased: uint tmp[E])  xs0 f32[M,22]  -> h2 bf16[M,128]
  float* B=(float*)alloc((size_t)M*256);   // Y1  f32[M,22]  -> ts  bf16[M,64]
  float* C=(float*)alloc((size_t)M*256);   // xs1 bf16[M,64] -> h3  f32[M,64]
  float* D=(float*)alloc((size_t)M*256);   // Y2  f32[M,64]
  unsigned* tmp=(unsigned*)A;              // E*4 bytes <= M*256 bytes
  (void)ws_size;(void)n_in;(void)out_size;

  hipMemsetAsync(bcnt,0,256*4,stream);
  coarsehist_kernel<<<512,256,0,stream>>>(dstp,bcnt,E,NB);
  binscan_kernel<<<1,256,0,stream>>>(bcnt,binoffs,bincur,NB,E);
  chunkscatter_kernel<<<(E+CHUNK-1)/CHUNK,256,0,stream>>>(srcp,dstp,bincur,tmp,E,NB,CHUNK);
  binsort_kernel<<<NB,256,0,stream>>>(tmp,binoffs,offs,deg,dinv,col,M);

  // layer 1: aggregate in 21-dim, then GEMM 21->64 (bias+relu+dinv into xs1, bf16)
  scale_kernel<<<(M*11+255)/256,256,0,stream>>>(x,dinv,A,M);
  agg_kernel<16,11,false,false><<<(M*16+255)/256,256,0,stream>>>(A,col,offs,deg,dinv,nullptr,B,M);
  gemm_kernel<22,21,64,64,false,true,true,true><<<(M+63)/64,256,0,stream>>>(B,W1,b1,dinv,C,M);
  // layer 2: aggregate in 64-dim bf16 (pre-GEMM), then GEMM 64->128 (bias+relu), h2 in bf16
  agg_kernel<32,32,false,true><<<(M*32+255)/256,256,0,stream>>>(C,col,offs,deg,dinv,nullptr,D,M);
  gemm_kernel<64,64,128,64,false,true,true,false><<<(M+63)/64,256,0,stream>>>(D,W2,b2,nullptr,A,M);
  // layer 3: GEMM 128->64 first (dinv into ts, bf16), then aggregate (bias+relu epilogue)
  gemm_kernel<128,128,64,32,true,true,false,true><<<(M+31)/32,256,0,stream>>>(A,W3,nullptr,dinv,B,M);
  agg_kernel<32,32,true,true><<<(M*32+255)/256,256,0,stream>>>(B,col,offs,deg,dinv,b3,C,M);
  // MLP head
  mlp_kernel<<<(M+255)/256,256,0,stream>>>(C,Wl1,bl1,Wl2,bl2,(float*)d_out,M);
}

// Round 5
// 435.400 us; speedup vs baseline: 3.5338x; 1.0975x over previous
//
#include <hip/hip_runtime.h>

#define DEV static __device__ __forceinline__

DEV float bf2f(unsigned short u){ union{unsigned i; float f;} a; a.i=((unsigned)u)<<16; return a.f; }
DEV unsigned short f2bf(float f){ union{unsigned i; float f;} a; a.f=f; unsigned r=a.i+0x7fffu+((a.i>>16)&1u); return (unsigned short)(r>>16); }
DEV float2 bfu2f2(unsigned v){ union{unsigned i; float f;} lo,hi; lo.i=v<<16; hi.i=v&0xffff0000u; return make_float2(lo.f,hi.f); }

// Coarse bins: 512 nodes each. Edge packed as src | (dst&511)<<23  (src < 2^23).
#define CB_SHIFT 9
#define CB_NODES 512
#define PK_SHIFT 23
#define PK_MASK  0x7fffffu

// ---------------- pass 0: coarse histogram (LDS-privatized) ----------------
__global__ __launch_bounds__(256) void coarsehist_kernel(const int* __restrict__ dst,
    int* __restrict__ bcnt, int E, int NB){
  __shared__ int h[256];
  int t=threadIdx.x;
  h[t]=0; __syncthreads();
  int i=blockIdx.x*256+t, st=gridDim.x*256;
  for(;i<E;i+=st) atomicAdd(&h[dst[i]>>CB_SHIFT],1);
  __syncthreads();
  if(t<NB && h[t]) atomicAdd(&bcnt[t],h[t]);
}

// ---------------- bin scan (1 block) ----------------
__global__ __launch_bounds__(256) void binscan_kernel(const int* __restrict__ bcnt,
    int* __restrict__ binoffs, int* __restrict__ bincur, int NB, int E){
  __shared__ int s[256];
  int t=threadIdx.x;
  int v=(t<NB)?bcnt[t]:0;
  s[t]=v; __syncthreads();
  for(int o=1;o<256;o<<=1){
    int u=(t>=o)?s[t-o]:0;
    __syncthreads();
    if(t>=o) s[t]+=u;
    __syncthreads();
  }
  int ex=s[t]-v;
  if(t<NB){ binoffs[t]=ex; bincur[t]=ex; }
  if(t==0) binoffs[NB]=E;
}

// ---------------- pass 1: chunked ranked scatter into coarse-bin windows ----------------
__global__ __launch_bounds__(256) void chunkscatter_kernel(const int* __restrict__ src,
    const int* __restrict__ dst, int* __restrict__ bincur, unsigned* __restrict__ tmp,
    int E, int NB, int C){
  __shared__ int lcnt[256];
  __shared__ int lbase[256];
  int t=threadIdx.x;
  lcnt[t]=0; __syncthreads();
  int e0=blockIdx.x*C, e1=min(e0+C,E);
  for(int i=e0+t;i<e1;i+=256) atomicAdd(&lcnt[dst[i]>>CB_SHIFT],1);
  __syncthreads();
  if(t<NB){ int c=lcnt[t]; lbase[t]=c?atomicAdd(&bincur[t],c):0; }
  __syncthreads();
  lcnt[t]=0; __syncthreads();
  for(int i=e0+t;i<e1;i+=256){
    int d=dst[i];
    int b=d>>CB_SHIFT;
    int r=atomicAdd(&lcnt[b],1);
    tmp[lbase[b]+r]=(unsigned)src[i]|((unsigned)(d&(CB_NODES-1))<<PK_SHIFT);
  }
}

// ---------------- pass 2: per-bin node sort; emits offs/deg/dinv/col ----------------
__global__ __launch_bounds__(256) void binsort_kernel(const unsigned* __restrict__ tmp,
    const int* __restrict__ binoffs, int* __restrict__ offs, int* __restrict__ deg,
    float* __restrict__ dinv, int* __restrict__ col, int M){
  __shared__ int cnt[CB_NODES];
  __shared__ int cur[CB_NODES];
  __shared__ int ssum[256];
  int b=blockIdx.x, t=threadIdx.x;
  int n0=b*CB_NODES;
  int e0=binoffs[b], e1=binoffs[b+1];
  cnt[2*t]=0; cnt[2*t+1]=0;
  __syncthreads();
  for(int i=e0+t;i<e1;i+=256) atomicAdd(&cnt[tmp[i]>>PK_SHIFT],1);
  __syncthreads();
  int a=cnt[2*t], c=cnt[2*t+1];
  ssum[t]=a+c; __syncthreads();
  for(int o=1;o<256;o<<=1){
    int u=(t>=o)?ssum[t-o]:0;
    __syncthreads();
    if(t>=o) ssum[t]+=u;
    __syncthreads();
  }
  int ex=e0+ssum[t]-(a+c);
  cur[2*t]=ex; cur[2*t+1]=ex+a;
  int na=n0+2*t, nb=n0+2*t+1;
  if(na<M){ offs[na]=ex;   deg[na]=a; dinv[na]=rsqrtf((float)(a+1)); }
  if(nb<M){ offs[nb]=ex+a; deg[nb]=c; dinv[nb]=rsqrtf((float)(c+1)); }
  __syncthreads();
  for(int i=e0+t;i<e1;i+=256){
    unsigned p=tmp[i];
    int pos=atomicAdd(&cur[p>>PK_SHIFT],1);
    col[pos]=(int)(p&PK_MASK);
  }
}

// ---------------- xs0 = dinv * x -> bf16 [M,32] (dims>=21 zero) ----------------
__global__ __launch_bounds__(256) void scale_kernel(const float* __restrict__ x, const float* __restrict__ dinv,
    uint2* __restrict__ xs, int M){
  int idx=blockIdx.x*256+threadIdx.x;
  if(idx>=M*8) return;
  int n=idx>>3, l=idx&7;
  float dv=dinv[n];
  const float* xr=x+(size_t)n*21;
  int c=4*l;
  float f0=(c  <21)?xr[c  ]*dv:0.f;
  float f1=(c+1<21)?xr[c+1]*dv:0.f;
  float f2v=(c+2<21)?xr[c+2]*dv:0.f;
  float f3=(c+3<21)?xr[c+3]*dv:0.f;
  uint2 v;
  v.x=(unsigned)f2bf(f0)|((unsigned)f2bf(f1)<<16);
  v.y=(unsigned)f2bf(f2v)|((unsigned)f2bf(f3)<<16);
  xs[(size_t)n*8+l]=v;
}

// ---------------- aggregation body: out[d] = dinv[d]*(in[d] + sum in[src]) ----------------
// bf16 input rows of GROUP uint2 packs (4 dims/lane); f32 float4 output rows.
template<int GROUP,bool BR>
DEV void agg_body(const uint2* __restrict__ xs, const int* __restrict__ col,
    const int* __restrict__ offs, const int* __restrict__ deg, const float* __restrict__ dinv,
    const float* __restrict__ bias, float4* __restrict__ out, int M){
  int gid=blockIdx.x*256+threadIdx.x;
  int node=gid/GROUP, lane=gid%GROUP;
  if(node>=M) return;
  float a0,a1,a2,a3;
  {
    uint2 v=xs[(size_t)node*GROUP+lane];
    float2 p=bfu2f2(v.x), q=bfu2f2(v.y);
    a0=p.x; a1=p.y; a2=q.x; a3=q.y;
  }
  int e0=offs[node], d=deg[node];
  int i=0;
  for(;i+8<=d;i+=8){
    int s[8]; uint2 w[8];
    #pragma unroll
    for(int q=0;q<8;q++) s[q]=col[e0+i+q];
    #pragma unroll
    for(int q=0;q<8;q++) w[q]=xs[(size_t)s[q]*GROUP+lane];
    #pragma unroll
    for(int q=0;q<8;q++){
      float2 p=bfu2f2(w[q].x); a0+=p.x; a1+=p.y;
      p=bfu2f2(w[q].y); a2+=p.x; a3+=p.y;
    }
  }
  for(;i+4<=d;i+=4){
    int s[4]; uint2 w[4];
    #pragma unroll
    for(int q=0;q<4;q++) s[q]=col[e0+i+q];
    #pragma unroll
    for(int q=0;q<4;q++) w[q]=xs[(size_t)s[q]*GROUP+lane];
    #pragma unroll
    for(int q=0;q<4;q++){
      float2 p=bfu2f2(w[q].x); a0+=p.x; a1+=p.y;
      p=bfu2f2(w[q].y); a2+=p.x; a3+=p.y;
    }
  }
  for(;i<d;i++){
    uint2 w=xs[(size_t)col[e0+i]*GROUP+lane];
    float2 p=bfu2f2(w.x); a0+=p.x; a1+=p.y;
    p=bfu2f2(w.y); a2+=p.x; a3+=p.y;
  }
  float dv=dinv[node];
  a0*=dv; a1*=dv; a2*=dv; a3*=dv;
  if constexpr(BR){
    a0=fmaxf(a0+bias[4*lane  ],0.f);
    a1=fmaxf(a1+bias[4*lane+1],0.f);
    a2=fmaxf(a2+bias[4*lane+2],0.f);
    a3=fmaxf(a3+bias[4*lane+3],0.f);
  }
  out[(size_t)node*GROUP+lane]=make_float4(a0,a1,a2,a3);
}

__global__ __launch_bounds__(256) void agg1_kernel(const uint2* xs, const int* col, const int* offs,
    const int* deg, const float* dinv, float4* out, int M){
  agg_body<8,false>(xs,col,offs,deg,dinv,nullptr,out,M);
}
__global__ __launch_bounds__(256) void agg2_kernel(const uint2* xs, const int* col, const int* offs,
    const int* deg, const float* dinv, float4* out, int M){
  agg_body<16,false>(xs,col,offs,deg,dinv,nullptr,out,M);
}
__global__ __launch_bounds__(256) void agg3_kernel(const uint2* xs, const int* col, const int* offs,
    const int* deg, const float* dinv, const float* bias, float4* out, int M){
  agg_body<16,true>(xs,col,offs,deg,dinv,bias,out,M);
}

// ---------------- tiled GEMM body: Out[M,N] = epilogue(X[M,K] @ W[RK,N]) ----------------
template<int K,int RK,int N,int NB,bool INBF,bool OUTBF,bool BR,bool DV>
DEV void gemm_body(const void* __restrict__ Xin, const float* __restrict__ W,
    const float* __restrict__ bias, const float* __restrict__ dinv, void* __restrict__ Out, int M){
  __shared__ float Wl[K*N];
  __shared__ float Xl[NB*K];
  int tid=threadIdx.x;
  for(int i=tid;i<K*N;i+=256){ int r=i/N; Wl[i]=(r<RK)?W[i]:0.f; }
  int nbase=blockIdx.x*NB;
  if constexpr(!INBF){
    const float* X=(const float*)Xin;
    for(int i=tid;i<NB*K;i+=256){ int r=i/K, c=i-r*K; int n=nbase+r; Xl[i]=(n<M)?X[(size_t)n*K+c]:0.f; }
  } else {
    const unsigned short* X=(const unsigned short*)Xin;
    for(int i=tid;i<NB*K;i+=256){ int r=i/K, c=i-r*K; int n=nbase+r; Xl[i]=(n<M)?bf2f(X[(size_t)n*K+c]):0.f; }
  }
  __syncthreads();
  constexpr int ROWS=NB/4;
  constexpr int NC=N/64;
  int lane=tid&63, wave=tid>>6;
  int rowbase=wave*ROWS;
  float acc[ROWS][NC];
  #pragma unroll
  for(int i=0;i<ROWS;i++)
    #pragma unroll
    for(int j=0;j<NC;j++) acc[i][j]=0.f;

  for(int k=0;k<K;k+=4){
    float wv[4][NC];
    #pragma unroll
    for(int q=0;q<4;q++)
      #pragma unroll
      for(int j=0;j<NC;j++) wv[q][j]=Wl[(k+q)*N+j*64+lane];
    #pragma unroll
    for(int i=0;i<ROWS;i++){
      float4 xv=*(const float4*)&Xl[(rowbase+i)*K+k];
      #pragma unroll
      for(int j=0;j<NC;j++){
        acc[i][j]=fmaf(xv.x,wv[0][j],acc[i][j]);
        acc[i][j]=fmaf(xv.y,wv[1][j],acc[i][j]);
        acc[i][j]=fmaf(xv.z,wv[2][j],acc[i][j]);
        acc[i][j]=fmaf(xv.w,wv[3][j],acc[i][j]);
      }
    }
  }
  float bv[NC];
  if constexpr(BR){
    #pragma unroll
    for(int j=0;j<NC;j++) bv[j]=bias[j*64+lane];
  }
  #pragma unroll
  for(int i=0;i<ROWS;i++){
    int n=nbase+rowbase+i;
    if(n<M){
      float dv=1.f;
      if constexpr(DV) dv=dinv[n];
      #pragma unroll
      for(int j=0;j<NC;j++){
        float v=acc[i][j];
        if constexpr(BR) v=fmaxf(v+bv[j],0.f);
        if constexpr(DV) v*=dv;
        int c=j*64+lane;
        if constexpr(OUTBF) ((unsigned short*)Out)[(size_t)n*N+c]=f2bf(v);
        else ((float*)Out)[(size_t)n*N+c]=v;
      }
    }
  }
}

__global__ __launch_bounds__(256) void gemm1_kernel(const void* X, const float* W, const float* bias,
    const float* dinv, void* Out, int M){
  gemm_body<32,21,64,64,false,true,true,true>(X,W,bias,dinv,Out,M);
}
__global__ __launch_bounds__(256) void gemm2_kernel(const void* X, const float* W, const float* bias,
    const float* dinv, void* Out, int M){
  gemm_body<64,64,128,64,false,true,true,false>(X,W,bias,dinv,Out,M);
}
__global__ __launch_bounds__(256) void gemm3_kernel(const void* X, const float* W, const float* bias,
    const float* dinv, void* Out, int M){
  gemm_body<128,128,64,32,true,true,false,true>(X,W,bias,dinv,Out,M);
}

// ---------------- fused MLP head: out = (relu(h@Wl1+bl1))@Wl2 + bl2 ----------------
__global__ __launch_bounds__(256) void mlp_kernel(const float* __restrict__ h, const float* __restrict__ W1,
    const float* __restrict__ b1, const float* __restrict__ W2, const float* __restrict__ b2,
    float* __restrict__ out, int M){
  __shared__ float W1s[64*20];
  __shared__ float b1s[20];
  __shared__ float W2s[20];
  __shared__ float b2s;
  int tid=threadIdx.x;
  for(int i=tid;i<1280;i+=256) W1s[i]=W1[i];
  if(tid<20){ b1s[tid]=b1[tid]; W2s[tid]=W2[tid]; }
  if(tid==0) b2s=b2[0];
  __syncthreads();
  int n=blockIdx.x*256+tid;
  if(n>=M) return;
  float acc[20];
  #pragma unroll
  for(int j=0;j<20;j++) acc[j]=b1s[j];
  const float4* hp=(const float4*)(h+(size_t)n*64);
  for(int k4=0;k4<16;k4++){
    float4 hv=hp[k4];
    #pragma unroll
    for(int j=0;j<20;j++){
      acc[j]=fmaf(hv.x,W1s[(k4*4+0)*20+j],acc[j]);
      acc[j]=fmaf(hv.y,W1s[(k4*4+1)*20+j],acc[j]);
      acc[j]=fmaf(hv.z,W1s[(k4*4+2)*20+j],acc[j]);
      acc[j]=fmaf(hv.w,W1s[(k4*4+3)*20+j],acc[j]);
    }
  }
  float r=b2s;
  #pragma unroll
  for(int j=0;j<20;j++) r+=fmaxf(acc[j],0.f)*W2s[j];
  out[n]=r;
}

extern "C" void kernel_launch(void* const* d_in, const int* in_sizes, int n_in,
                              void* d_out, int out_size, void* d_ws, size_t ws_size,
                              hipStream_t stream){
  const float* x  =(const float*)d_in[0];
  const int*   ei =(const int*)  d_in[1];
  const float* W1 =(const float*)d_in[2];
  const float* b1 =(const float*)d_in[3];
  const float* W2 =(const float*)d_in[4];
  const float* b2 =(const float*)d_in[5];
  const float* W3 =(const float*)d_in[6];
  const float* b3 =(const float*)d_in[7];
  const float* Wl1=(const float*)d_in[8];
  const float* bl1=(const float*)d_in[9];
  const float* Wl2=(const float*)d_in[10];
  const float* bl2=(const float*)d_in[11];
  const int M=in_sizes[0]/21;
  const int E=in_sizes[1]/2;
  const int* srcp=ei;
  const int* dstp=ei+(size_t)E;
  const int NB=(M+CB_NODES-1)/CB_NODES;   // coarse bins (<=256 for M<=131072)
  const int CHUNK=4096;

  char* ws=(char*)d_ws;
  size_t off=0;
  auto alloc=[&](size_t bytes)->void*{
    off=(off+255)&~(size_t)255;
    void* p=ws+off; off+=bytes; return p;
  };
  int*   offs   =(int*)  alloc((size_t)M*4);
  int*   deg    =(int*)  alloc((size_t)M*4);
  float* dinv   =(float*)alloc((size_t)M*4);
  int*   bcnt   =(int*)  alloc(256*4);
  int*   binoffs=(int*)  alloc(257*4);
  int*   bincur =(int*)  alloc(256*4);
  int*   col    =(int*)  alloc((size_t)E*4);
  // four reusable 256B-per-node slots
  float* A=(float*)alloc((size_t)M*256);   // (alias: uint tmp[E]) xs0 bf16[M,32] -> h2 bf16[M,128]
  float* B=(float*)alloc((size_t)M*256);   // Y1 f32[M,32] -> ts bf16[M,64]
  float* C=(float*)alloc((size_t)M*256);   // xs1 bf16[M,64] -> h3 f32[M,64]
  float* D=(float*)alloc((size_t)M*256);   // Y2 f32[M,64]
  unsigned* tmp=(unsigned*)A;              // E*4 bytes <= M*256 bytes
  (void)ws_size;(void)n_in;(void)out_size;

  hipMemsetAsync(bcnt,0,256*4,stream);
  coarsehist_kernel<<<512,256,0,stream>>>(dstp,bcnt,E,NB);
  binscan_kernel<<<1,256,0,stream>>>(bcnt,binoffs,bincur,NB,E);
  chunkscatter_kernel<<<(E+CHUNK-1)/CHUNK,256,0,stream>>>(srcp,dstp,bincur,tmp,E,NB,CHUNK);
  binsort_kernel<<<NB,256,0,stream>>>(tmp,binoffs,offs,deg,dinv,col,M);

  // layer 1: xs0 bf16[M,32]; aggregate (GROUP=8); GEMM 21->64 (bias+relu+dinv, out bf16)
  scale_kernel<<<(M*8+255)/256,256,0,stream>>>(x,dinv,(uint2*)A,M);
  agg1_kernel<<<(M*8+255)/256,256,0,stream>>>((const uint2*)A,col,offs,deg,dinv,(float4*)B,M);
  gemm1_kernel<<<(M+63)/64,256,0,stream>>>(B,W1,b1,dinv,C,M);
  // layer 2: aggregate bf16 (GROUP=16); GEMM 64->128 (bias+relu), h2 bf16
  agg2_kernel<<<(M*16+255)/256,256,0,stream>>>((const uint2*)C,col,offs,deg,dinv,(float4*)D,M);
  gemm2_kernel<<<(M+63)/64,256,0,stream>>>(D,W2,b2,nullptr,A,M);
  // layer 3: GEMM 128->64 first (dinv, out bf16 ts), then aggregate (bias+relu epilogue)
  gemm3_kernel<<<(M+31)/32,256,0,stream>>>(A,W3,nullptr,dinv,B,M);
  agg3_kernel<<<(M*16+255)/256,256,0,stream>>>((const uint2*)B,col,offs,deg,dinv,b3,(float4*)C,M);
  // MLP head
  mlp_kernel<<<(M+255)/256,256,0,stream>>>(C,Wl1,bl1,Wl2,bl2,(float*)d_out,M);
}

// Round 6
// 366.608 us; speedup vs baseline: 4.1969x; 1.1876x over previous
//
#include <hip/hip_runtime.h>

#define DEV static __device__ __forceinline__

typedef __attribute__((ext_vector_type(8))) short short8;
typedef __attribute__((ext_vector_type(4))) float f32x4;

DEV float bf2f(unsigned short u){ union{unsigned i; float f;} a; a.i=((unsigned)u)<<16; return a.f; }
DEV unsigned short f2bf(float f){ union{unsigned i; float f;} a; a.f=f; unsigned r=a.i+0x7fffu+((a.i>>16)&1u); return (unsigned short)(r>>16); }
DEV float2 bfu2f2(unsigned v){ union{unsigned i; float f;} lo,hi; lo.i=v<<16; hi.i=v&0xffff0000u; return make_float2(lo.f,hi.f); }

// Coarse bins: 512 nodes each. Edge packed as src | (dst&511)<<23  (src < 2^23).
#define CB_SHIFT 9
#define CB_NODES 512
#define PK_SHIFT 23
#define PK_MASK  0x7fffffu

// ---------------- pass 0: coarse histogram (LDS-privatized) ----------------
__global__ __launch_bounds__(256) void coarsehist_kernel(const int* __restrict__ dst,
    int* __restrict__ bcnt, int E, int NB){
  __shared__ int h[256];
  int t=threadIdx.x;
  h[t]=0; __syncthreads();
  int i=blockIdx.x*256+t, st=gridDim.x*256;
  for(;i<E;i+=st) atomicAdd(&h[dst[i]>>CB_SHIFT],1);
  __syncthreads();
  if(t<NB && h[t]) atomicAdd(&bcnt[t],h[t]);
}

// ---------------- bin scan (1 block) ----------------
__global__ __launch_bounds__(256) void binscan_kernel(const int* __restrict__ bcnt,
    int* __restrict__ binoffs, int* __restrict__ bincur, int NB, int E){
  __shared__ int s[256];
  int t=threadIdx.x;
  int v=(t<NB)?bcnt[t]:0;
  s[t]=v; __syncthreads();
  for(int o=1;o<256;o<<=1){
    int u=(t>=o)?s[t-o]:0;
    __syncthreads();
    if(t>=o) s[t]+=u;
    __syncthreads();
  }
  int ex=s[t]-v;
  if(t<NB){ binoffs[t]=ex; bincur[t]=ex; }
  if(t==0) binoffs[NB]=E;
}

// ---------------- pass 1: chunked ranked scatter into coarse-bin windows ----------------
__global__ __launch_bounds__(256) void chunkscatter_kernel(const int* __restrict__ src,
    const int* __restrict__ dst, int* __restrict__ bincur, unsigned* __restrict__ tmp,
    int E, int NB, int C){
  __shared__ int lcnt[256];
  __shared__ int lbase[256];
  int t=threadIdx.x;
  lcnt[t]=0; __syncthreads();
  int e0=blockIdx.x*C, e1=min(e0+C,E);
  for(int i=e0+t;i<e1;i+=256) atomicAdd(&lcnt[dst[i]>>CB_SHIFT],1);
  __syncthreads();
  if(t<NB){ int c=lcnt[t]; lbase[t]=c?atomicAdd(&bincur[t],c):0; }
  __syncthreads();
  lcnt[t]=0; __syncthreads();
  for(int i=e0+t;i<e1;i+=256){
    int d=dst[i];
    int b=d>>CB_SHIFT;
    int r=atomicAdd(&lcnt[b],1);
    tmp[lbase[b]+r]=(unsigned)src[i]|((unsigned)(d&(CB_NODES-1))<<PK_SHIFT);
  }
}

// ---------------- pass 2: per-bin node sort; emits offs/deg/dinv/col ----------------
__global__ __launch_bounds__(256) void binsort_kernel(const unsigned* __restrict__ tmp,
    const int* __restrict__ binoffs, int* __restrict__ offs, int* __restrict__ deg,
    float* __restrict__ dinv, int* __restrict__ col, int M){
  __shared__ int cnt[CB_NODES];
  __shared__ int cur[CB_NODES];
  __shared__ int ssum[256];
  int b=blockIdx.x, t=threadIdx.x;
  int n0=b*CB_NODES;
  int e0=binoffs[b], e1=binoffs[b+1];
  cnt[2*t]=0; cnt[2*t+1]=0;
  __syncthreads();
  for(int i=e0+t;i<e1;i+=256) atomicAdd(&cnt[tmp[i]>>PK_SHIFT],1);
  __syncthreads();
  int a=cnt[2*t], c=cnt[2*t+1];
  ssum[t]=a+c; __syncthreads();
  for(int o=1;o<256;o<<=1){
    int u=(t>=o)?ssum[t-o]:0;
    __syncthreads();
    if(t>=o) ssum[t]+=u;
    __syncthreads();
  }
  int ex=e0+ssum[t]-(a+c);
  cur[2*t]=ex; cur[2*t+1]=ex+a;
  int na=n0+2*t, nb=n0+2*t+1;
  if(na<M){ offs[na]=ex;   deg[na]=a; dinv[na]=rsqrtf((float)(a+1)); }
  if(nb<M){ offs[nb]=ex+a; deg[nb]=c; dinv[nb]=rsqrtf((float)(c+1)); }
  __syncthreads();
  for(int i=e0+t;i<e1;i+=256){
    unsigned p=tmp[i];
    int pos=atomicAdd(&cur[p>>PK_SHIFT],1);
    col[pos]=(int)(p&PK_MASK);
  }
}

// ---------------- xs0 = dinv * x -> bf16 [M,32] (dims>=21 zero) ----------------
__global__ __launch_bounds__(256) void scale_kernel(const float* __restrict__ x, const float* __restrict__ dinv,
    uint2* __restrict__ xs, int M){
  int idx=blockIdx.x*256+threadIdx.x;
  if(idx>=M*8) return;
  int n=idx>>3, l=idx&7;
  float dv=dinv[n];
  const float* xr=x+(size_t)n*21;
  int c=4*l;
  float f0=(c  <21)?xr[c  ]*dv:0.f;
  float f1=(c+1<21)?xr[c+1]*dv:0.f;
  float f2v=(c+2<21)?xr[c+2]*dv:0.f;
  float f3=(c+3<21)?xr[c+3]*dv:0.f;
  uint2 v;
  v.x=(unsigned)f2bf(f0)|((unsigned)f2bf(f1)<<16);
  v.y=(unsigned)f2bf(f2v)|((unsigned)f2bf(f3)<<16);
  xs[(size_t)n*8+l]=v;
}

// ---------------- aggregation body: out[d] = dinv[d]*(in[d] + sum in[src]) ----------------
// bf16 input rows of GROUP uint2 packs (4 dims/lane); output f32 float4 or bf16 uint2 rows.
template<int GROUP,bool BR,bool OUTBF>
DEV void agg_body(const uint2* __restrict__ xs, const int* __restrict__ col,
    const int* __restrict__ offs, const int* __restrict__ deg, const float* __restrict__ dinv,
    const float* __restrict__ bias, void* __restrict__ out, int M){
  int gid=blockIdx.x*256+threadIdx.x;
  int node=gid/GROUP, lane=gid%GROUP;
  if(node>=M) return;
  float a0,a1,a2,a3;
  {
    uint2 v=xs[(size_t)node*GROUP+lane];
    float2 p=bfu2f2(v.x), q=bfu2f2(v.y);
    a0=p.x; a1=p.y; a2=q.x; a3=q.y;
  }
  int e0=offs[node], d=deg[node];
  int i=0;
  for(;i+8<=d;i+=8){
    int s[8]; uint2 w[8];
    #pragma unroll
    for(int q=0;q<8;q++) s[q]=col[e0+i+q];
    #pragma unroll
    for(int q=0;q<8;q++) w[q]=xs[(size_t)s[q]*GROUP+lane];
    #pragma unroll
    for(int q=0;q<8;q++){
      float2 p=bfu2f2(w[q].x); a0+=p.x; a1+=p.y;
      p=bfu2f2(w[q].y); a2+=p.x; a3+=p.y;
    }
  }
  for(;i+4<=d;i+=4){
    int s[4]; uint2 w[4];
    #pragma unroll
    for(int q=0;q<4;q++) s[q]=col[e0+i+q];
    #pragma unroll
    for(int q=0;q<4;q++) w[q]=xs[(size_t)s[q]*GROUP+lane];
    #pragma unroll
    for(int q=0;q<4;q++){
      float2 p=bfu2f2(w[q].x); a0+=p.x; a1+=p.y;
      p=bfu2f2(w[q].y); a2+=p.x; a3+=p.y;
    }
  }
  for(;i<d;i++){
    uint2 w=xs[(size_t)col[e0+i]*GROUP+lane];
    float2 p=bfu2f2(w.x); a0+=p.x; a1+=p.y;
    p=bfu2f2(w.y); a2+=p.x; a3+=p.y;
  }
  float dv=dinv[node];
  a0*=dv; a1*=dv; a2*=dv; a3*=dv;
  if constexpr(BR){
    a0=fmaxf(a0+bias[4*lane  ],0.f);
    a1=fmaxf(a1+bias[4*lane+1],0.f);
    a2=fmaxf(a2+bias[4*lane+2],0.f);
    a3=fmaxf(a3+bias[4*lane+3],0.f);
  }
  if constexpr(OUTBF){
    uint2 v;
    v.x=(unsigned)f2bf(a0)|((unsigned)f2bf(a1)<<16);
    v.y=(unsigned)f2bf(a2)|((unsigned)f2bf(a3)<<16);
    ((uint2*)out)[(size_t)node*GROUP+lane]=v;
  } else {
    ((float4*)out)[(size_t)node*GROUP+lane]=make_float4(a0,a1,a2,a3);
  }
}

__global__ __launch_bounds__(256) void agg1_kernel(const uint2* xs, const int* col, const int* offs,
    const int* deg, const float* dinv, float4* out, int M){
  agg_body<8,false,false>(xs,col,offs,deg,dinv,nullptr,out,M);
}
__global__ __launch_bounds__(256) void agg2_kernel(const uint2* xs, const int* col, const int* offs,
    const int* deg, const float* dinv, uint2* out, int M){
  agg_body<16,false,true>(xs,col,offs,deg,dinv,nullptr,out,M);
}
__global__ __launch_bounds__(256) void agg3_kernel(const uint2* xs, const int* col, const int* offs,
    const int* deg, const float* dinv, const float* bias, float4* out, int M){
  agg_body<16,true,false>(xs,col,offs,deg,dinv,bias,out,M);
}

// ---------------- f32 tiled GEMM (layer 1 only): Out = relu(X@W+b)*dinv, bf16 ----------------
template<int K,int RK,int N,int NB>
DEV void gemm_body(const float* __restrict__ X, const float* __restrict__ W,
    const float* __restrict__ bias, const float* __restrict__ dinv, unsigned short* __restrict__ Out, int M){
  __shared__ float Wl[K*N];
  __shared__ float Xl[NB*K];
  int tid=threadIdx.x;
  for(int i=tid;i<K*N;i+=256){ int r=i/N; Wl[i]=(r<RK)?W[i]:0.f; }
  int nbase=blockIdx.x*NB;
  for(int i=tid;i<NB*K;i+=256){ int r=i/K, c=i-r*K; int n=nbase+r; Xl[i]=(n<M)?X[(size_t)n*K+c]:0.f; }
  __syncthreads();
  constexpr int ROWS=NB/4;
  constexpr int NC=N/64;
  int lane=tid&63, wave=tid>>6;
  int rowbase=wave*ROWS;
  float acc[ROWS][NC];
  #pragma unroll
  for(int i=0;i<ROWS;i++)
    #pragma unroll
    for(int j=0;j<NC;j++) acc[i][j]=0.f;

  for(int k=0;k<K;k+=4){
    float wv[4][NC];
    #pragma unroll
    for(int q=0;q<4;q++)
      #pragma unroll
      for(int j=0;j<NC;j++) wv[q][j]=Wl[(k+q)*N+j*64+lane];
    #pragma unroll
    for(int i=0;i<ROWS;i++){
      float4 xv=*(const float4*)&Xl[(rowbase+i)*K+k];
      #pragma unroll
      for(int j=0;j<NC;j++){
        acc[i][j]=fmaf(xv.x,wv[0][j],acc[i][j]);
        acc[i][j]=fmaf(xv.y,wv[1][j],acc[i][j]);
        acc[i][j]=fmaf(xv.z,wv[2][j],acc[i][j]);
        acc[i][j]=fmaf(xv.w,wv[3][j],acc[i][j]);
      }
    }
  }
  float bv[NC];
  #pragma unroll
  for(int j=0;j<NC;j++) bv[j]=bias[j*64+lane];
  #pragma unroll
  for(int i=0;i<ROWS;i++){
    int n=nbase+rowbase+i;
    if(n<M){
      float dv=dinv[n];
      #pragma unroll
      for(int j=0;j<NC;j++){
        float v=fmaxf(acc[i][j]+bv[j],0.f)*dv;
        Out[(size_t)n*N+j*64+lane]=f2bf(v);
      }
    }
  }
}

__global__ __launch_bounds__(256) void gemm1_kernel(const float* X, const float* W, const float* bias,
    const float* dinv, unsigned short* Out, int M){
  gemm_body<32,21,64,64>(X,W,bias,dinv,Out,M);
}

// ---------------- W prep: split f32 W[K][N] into frag-ready bf16 hi/lo ----------------
// Layout: idx = ((nt*KS+ks)*64 + lane)*8 + j ; elem = W[ks*32+(lane>>4)*8+j][nt*16+(lane&15)]
__global__ __launch_bounds__(256) void wprep_kernel(const float* __restrict__ W,
    unsigned short* __restrict__ Warr, int KS, int N, int KN){
  int idx=blockIdx.x*256+threadIdx.x;
  if(idx>=KN) return;
  int j=idx&7, l=(idx>>3)&63, t=idx>>9;
  int ks=t%KS, nt=t/KS;
  int k=ks*32+((l>>4)<<3)+j;
  int c=nt*16+(l&15);
  float w=W[(size_t)k*N+c];
  unsigned short hi=f2bf(w);
  unsigned short lo=f2bf(w-bf2f(hi));
  Warr[idx]=hi;
  Warr[KN+idx]=lo;
}

// ---------------- MFMA GEMM (no LDS): Out[M,N]=epi(Xbf16[M,K] @ (Whi+Wlo)) ----------------
// A-frag: row=lane&15, k=ks*32+(lane>>4)*8+j (16B contiguous). B-frag from Warr. 
// C/D: col=lane&15, row=(lane>>4)*4+reg.
template<int K,int NT,bool BR,bool DV>
DEV void mfma_gemm_body(const unsigned short* __restrict__ X, const unsigned short* __restrict__ Warr,
    const float* __restrict__ bias, const float* __restrict__ dinv, unsigned short* __restrict__ Out, int M){
  constexpr int KS=K/32;
  constexpr int N=NT*16;
  constexpr int KN=K*N;
  int tid=threadIdx.x;
  int lane=tid&63, wave=tid>>6;
  int rowbase=blockIdx.x*64+wave*16;
  int r=rowbase+(lane&15);
  int rc=min(r,M-1);
  const short* Xr=(const short*)(X+(size_t)rc*K+((lane>>4)<<3));
  short8 af[KS];
  #pragma unroll
  for(int ks=0;ks<KS;ks++) af[ks]=*(const short8*)(Xr+ks*32);
  const short* wp=(const short*)Warr+lane*8;
  int colv=lane&15;
  #pragma unroll
  for(int nt=0;nt<NT;nt++){
    f32x4 acc={0.f,0.f,0.f,0.f};
    const short* wnt=wp+nt*KS*512;
    #pragma unroll
    for(int ks=0;ks<KS;ks++){
      short8 bh=*(const short8*)(wnt+ks*512);
      short8 bl=*(const short8*)(wnt+KN+ks*512);
      acc=__builtin_amdgcn_mfma_f32_16x16x32_bf16(af[ks],bh,acc,0,0,0);
      acc=__builtin_amdgcn_mfma_f32_16x16x32_bf16(af[ks],bl,acc,0,0,0);
    }
    int c=nt*16+colv;
    float bv=0.f;
    if constexpr(BR) bv=bias[c];
    #pragma unroll
    for(int reg=0;reg<4;reg++){
      int row=rowbase+((lane>>4)<<2)+reg;
      if(row<M){
        float v=acc[reg];
        if constexpr(BR) v=fmaxf(v+bv,0.f);
        if constexpr(DV) v*=dinv[row];
        Out[(size_t)row*N+c]=f2bf(v);
      }
    }
  }
}

__global__ __launch_bounds__(256) void gemm2m_kernel(const unsigned short* X, const unsigned short* Warr,
    const float* bias, unsigned short* Out, int M){
  mfma_gemm_body<64,8,true,false>(X,Warr,bias,nullptr,Out,M);
}
__global__ __launch_bounds__(256) void gemm3m_kernel(const unsigned short* X, const unsigned short* Warr,
    const float* dinv, unsigned short* Out, int M){
  mfma_gemm_body<128,4,false,true>(X,Warr,nullptr,dinv,Out,M);
}

// ---------------- fused MLP head: out = (relu(h@Wl1+bl1))@Wl2 + bl2 ----------------
__global__ __launch_bounds__(256) void mlp_kernel(const float* __restrict__ h, const float* __restrict__ W1,
    const float* __restrict__ b1, const float* __restrict__ W2, const float* __restrict__ b2,
    float* __restrict__ out, int M){
  __shared__ float W1s[64*20];
  __shared__ float b1s[20];
  __shared__ float W2s[20];
  __shared__ float b2s;
  int tid=threadIdx.x;
  for(int i=tid;i<1280;i+=256) W1s[i]=W1[i];
  if(tid<20){ b1s[tid]=b1[tid]; W2s[tid]=W2[tid]; }
  if(tid==0) b2s=b2[0];
  __syncthreads();
  int n=blockIdx.x*256+tid;
  if(n>=M) return;
  float acc[20];
  #pragma unroll
  for(int j=0;j<20;j++) acc[j]=b1s[j];
  const float4* hp=(const float4*)(h+(size_t)n*64);
  for(int k4=0;k4<16;k4++){
    float4 hv=hp[k4];
    #pragma unroll
    for(int j=0;j<20;j++){
      acc[j]=fmaf(hv.x,W1s[(k4*4+0)*20+j],acc[j]);
      acc[j]=fmaf(hv.y,W1s[(k4*4+1)*20+j],acc[j]);
      acc[j]=fmaf(hv.z,W1s[(k4*4+2)*20+j],acc[j]);
      acc[j]=fmaf(hv.w,W1s[(k4*4+3)*20+j],acc[j]);
    }
  }
  float r=b2s;
  #pragma unroll
  for(int j=0;j<20;j++) r+=fmaxf(acc[j],0.f)*W2s[j];
  out[n]=r;
}

extern "C" void kernel_launch(void* const* d_in, const int* in_sizes, int n_in,
                              void* d_out, int out_size, void* d_ws, size_t ws_size,
                              hipStream_t stream){
  const float* x  =(const float*)d_in[0];
  const int*   ei =(const int*)  d_in[1];
  const float* W1 =(const float*)d_in[2];
  const float* b1 =(const float*)d_in[3];
  const float* W2 =(const float*)d_in[4];
  const float* b2 =(const float*)d_in[5];
  const float* W3 =(const float*)d_in[6];
  const float* b3 =(const float*)d_in[7];
  const float* Wl1=(const float*)d_in[8];
  const float* bl1=(const float*)d_in[9];
  const float* Wl2=(const float*)d_in[10];
  const float* bl2=(const float*)d_in[11];
  const int M=in_sizes[0]/21;
  const int E=in_sizes[1]/2;
  const int* srcp=ei;
  const int* dstp=ei+(size_t)E;
  const int NB=(M+CB_NODES-1)/CB_NODES;   // coarse bins (<=256 for M<=131072)
  const int CHUNK=4096;

  char* ws=(char*)d_ws;
  size_t off=0;
  auto alloc=[&](size_t bytes)->void*{
    off=(off+255)&~(size_t)255;
    void* p=ws+off; off+=bytes; return p;
  };
  int*   offs   =(int*)  alloc((size_t)M*4);
  int*   deg    =(int*)  alloc((size_t)M*4);
  float* dinv   =(float*)alloc((size_t)M*4);
  int*   bcnt   =(int*)  alloc(256*4);
  int*   binoffs=(int*)  alloc(257*4);
  int*   bincur =(int*)  alloc(256*4);
  unsigned short* W2arr=(unsigned short*)alloc(2*64*128*2);   // hi+lo
  unsigned short* W3arr=(unsigned short*)alloc(2*128*64*2);   // hi+lo
  int*   col    =(int*)  alloc((size_t)E*4);
  // four reusable 256B-per-node slots
  float* A=(float*)alloc((size_t)M*256);   // (alias: uint tmp[E]) xs0 bf16[M,32] -> h2 bf16[M,128]
  float* B=(float*)alloc((size_t)M*256);   // Y1 f32[M,32] -> ts bf16[M,64]
  float* C=(float*)alloc((size_t)M*256);   // xs1 bf16[M,64] -> h3 f32[M,64]
  float* D=(float*)alloc((size_t)M*256);   // Y2 bf16[M,64]
  unsigned* tmp=(unsigned*)A;              // E*4 bytes <= M*256 bytes
  (void)ws_size;(void)n_in;(void)out_size;

  hipMemsetAsync(bcnt,0,256*4,stream);
  coarsehist_kernel<<<512,256,0,stream>>>(dstp,bcnt,E,NB);
  binscan_kernel<<<1,256,0,stream>>>(bcnt,binoffs,bincur,NB,E);
  chunkscatter_kernel<<<(E+CHUNK-1)/CHUNK,256,0,stream>>>(srcp,dstp,bincur,tmp,E,NB,CHUNK);
  binsort_kernel<<<NB,256,0,stream>>>(tmp,binoffs,offs,deg,dinv,col,M);
  wprep_kernel<<<(64*128+255)/256,256,0,stream>>>(W2,W2arr,2,128,64*128);
  wprep_kernel<<<(128*64+255)/256,256,0,stream>>>(W3,W3arr,4,64,128*64);

  // layer 1: xs0 bf16[M,32]; aggregate (GROUP=8); f32 GEMM 21->64 (bias+relu+dinv, out bf16 xs1)
  scale_kernel<<<(M*8+255)/256,256,0,stream>>>(x,dinv,(uint2*)A,M);
  agg1_kernel<<<(M*8+255)/256,256,0,stream>>>((const uint2*)A,col,offs,deg,dinv,(float4*)B,M);
  gemm1_kernel<<<(M+63)/64,256,0,stream>>>(B,W1,b1,dinv,(unsigned short*)C,M);
  // layer 2: aggregate bf16 (GROUP=16, out bf16 Y2); MFMA GEMM 64->128 (bias+relu), h2 bf16
  agg2_kernel<<<(M*16+255)/256,256,0,stream>>>((const uint2*)C,col,offs,deg,dinv,(uint2*)D,M);
  gemm2m_kernel<<<(M+63)/64,256,0,stream>>>((const unsigned short*)D,W2arr,b2,(unsigned short*)A,M);
  // layer 3: MFMA GEMM 128->64 (dinv, out bf16 ts), then aggregate (bias+relu epilogue)
  gemm3m_kernel<<<(M+63)/64,256,0,stream>>>((const unsigned short*)A,W3arr,dinv,(unsigned short*)B,M);
  agg3_kernel<<<(M*16+255)/256,256,0,stream>>>((const uint2*)B,col,offs,deg,dinv,b3,(float4*)C,M);
  // MLP head
  mlp_kernel<<<(M+255)/256,256,0,stream>>>(C,Wl1,bl1,Wl2,bl2,(float*)d_out,M);
}

// Round 7
// 308.368 us; speedup vs baseline: 4.9896x; 1.1889x over previous
//
#include <hip/hip_runtime.h>

#define DEV static __device__ __forceinline__

typedef __attribute__((ext_vector_type(8))) short short8;
typedef __attribute__((ext_vector_type(4))) float f32x4;

DEV float bf2f(unsigned short u){ union{unsigned i; float f;} a; a.i=((unsigned)u)<<16; return a.f; }
DEV unsigned short f2bf(float f){ union{unsigned i; float f;} a; a.f=f; unsigned r=a.i+0x7fffu+((a.i>>16)&1u); return (unsigned short)(r>>16); }
DEV float2 bfu2f2(unsigned v){ union{unsigned i; float f;} lo,hi; lo.i=v<<16; hi.i=v&0xffff0000u; return make_float2(lo.f,hi.f); }

// Coarse bins: 512 nodes each. Edge packed as src | (dst&511)<<23  (src < 2^23).
#define CB_SHIFT 9
#define CB_NODES 512
#define PK_SHIFT 23
#define PK_MASK  0x7fffffu
#define CHUNK 4096

// ---------------- pass 0: coarse histogram (LDS-privatized) ----------------
__global__ __launch_bounds__(256) void coarsehist_kernel(const int* __restrict__ dst,
    int* __restrict__ bcnt, int E, int NB){
  __shared__ int h[256];
  int t=threadIdx.x;
  h[t]=0; __syncthreads();
  int i=blockIdx.x*256+t, st=gridDim.x*256;
  for(;i<E;i+=st) atomicAdd(&h[dst[i]>>CB_SHIFT],1);
  __syncthreads();
  if(t<NB && h[t]) atomicAdd(&bcnt[t],h[t]);
}

// ---------------- bin scan (1 block) ----------------
__global__ __launch_bounds__(256) void binscan_kernel(const int* __restrict__ bcnt,
    int* __restrict__ binoffs, int* __restrict__ bincur, int NB, int E){
  __shared__ int s[256];
  int t=threadIdx.x;
  int v=(t<NB)?bcnt[t]:0;
  s[t]=v; __syncthreads();
  for(int o=1;o<256;o<<=1){
    int u=(t>=o)?s[t-o]:0;
    __syncthreads();
    if(t>=o) s[t]+=u;
    __syncthreads();
  }
  int ex=s[t]-v;
  if(t<NB){ binoffs[t]=ex; bincur[t]=ex; }
  if(t==0) binoffs[NB]=E;
}

// ---------------- pass 1: chunked scatter, LDS bin-sorted for coalesced emission ----------------
__global__ __launch_bounds__(256) void chunkscatter_kernel(const int* __restrict__ src,
    const int* __restrict__ dst, int* __restrict__ bincur, unsigned* __restrict__ tmp,
    int E, int NB){
  __shared__ int lcnt[256];
  __shared__ int lstart[256];
  __shared__ int lbase[256];
  __shared__ unsigned pk[CHUNK];
  __shared__ int gaddr[CHUNK];
  int t=threadIdx.x;
  lcnt[t]=0; __syncthreads();
  int e0=blockIdx.x*CHUNK, e1=min(e0+CHUNK,E);
  int n=e1-e0;
  unsigned pkr[16]; int binr[16]; int rnk[16];
  #pragma unroll
  for(int q=0;q<16;q++){
    int i=e0+t+q*256;
    if(i<e1){
      int d=dst[i];
      int b=d>>CB_SHIFT;
      binr[q]=b;
      pkr[q]=(unsigned)src[i]|((unsigned)(d&(CB_NODES-1))<<PK_SHIFT);
      rnk[q]=atomicAdd(&lcnt[b],1);
    }
  }
  __syncthreads();
  int c=lcnt[t];
  lstart[t]=c; __syncthreads();
  for(int o=1;o<256;o<<=1){
    int u=(t>=o)?lstart[t-o]:0;
    __syncthreads();
    if(t>=o) lstart[t]+=u;
    __syncthreads();
  }
  int ex=lstart[t]-c;
  __syncthreads();
  lstart[t]=ex;
  lbase[t]=(t<NB&&c)?atomicAdd(&bincur[t],c):0;
  __syncthreads();
  #pragma unroll
  for(int q=0;q<16;q++){
    int i=e0+t+q*256;
    if(i<e1){
      int b=binr[q];
      int p=lstart[b]+rnk[q];
      pk[p]=pkr[q];
      gaddr[p]=lbase[b]+rnk[q];
    }
  }
  __syncthreads();
  for(int p=t;p<n;p+=256) tmp[gaddr[p]]=pk[p];
}

// ---------------- pass 2: per-bin node sort; emits offs/deg/dinv/col ----------------
__global__ __launch_bounds__(256) void binsort_kernel(const unsigned* __restrict__ tmp,
    const int* __restrict__ binoffs, int* __restrict__ offs, int* __restrict__ deg,
    float* __restrict__ dinv, int* __restrict__ col, int M){
  __shared__ int cnt[CB_NODES];
  __shared__ int cur[CB_NODES];
  __shared__ int ssum[256];
  int b=blockIdx.x, t=threadIdx.x;
  int n0=b*CB_NODES;
  int e0=binoffs[b], e1=binoffs[b+1];
  cnt[2*t]=0; cnt[2*t+1]=0;
  __syncthreads();
  for(int i=e0+t;i<e1;i+=256) atomicAdd(&cnt[tmp[i]>>PK_SHIFT],1);
  __syncthreads();
  int a=cnt[2*t], c=cnt[2*t+1];
  ssum[t]=a+c; __syncthreads();
  for(int o=1;o<256;o<<=1){
    int u=(t>=o)?ssum[t-o]:0;
    __syncthreads();
    if(t>=o) ssum[t]+=u;
    __syncthreads();
  }
  int ex=e0+ssum[t]-(a+c);
  cur[2*t]=ex; cur[2*t+1]=ex+a;
  int na=n0+2*t, nb=n0+2*t+1;
  if(na<M){ offs[na]=ex;   deg[na]=a; dinv[na]=rsqrtf((float)(a+1)); }
  if(nb<M){ offs[nb]=ex+a; deg[nb]=c; dinv[nb]=rsqrtf((float)(c+1)); }
  __syncthreads();
  for(int i=e0+t;i<e1;i+=256){
    unsigned p=tmp[i];
    int pos=atomicAdd(&cur[p>>PK_SHIFT],1);
    col[pos]=(int)(p&PK_MASK);
  }
}

// ---------------- xs0 = dinv * x -> bf16 [M,32] (dims>=21 zero) ----------------
__global__ __launch_bounds__(256) void scale_kernel(const float* __restrict__ x, const float* __restrict__ dinv,
    uint2* __restrict__ xs, int M){
  int idx=blockIdx.x*256+threadIdx.x;
  if(idx>=M*8) return;
  int n=idx>>3, l=idx&7;
  float dv=dinv[n];
  const float* xr=x+(size_t)n*21;
  int c=4*l;
  float f0=(c  <21)?xr[c  ]*dv:0.f;
  float f1=(c+1<21)?xr[c+1]*dv:0.f;
  float f2v=(c+2<21)?xr[c+2]*dv:0.f;
  float f3=(c+3<21)?xr[c+3]*dv:0.f;
  uint2 v;
  v.x=(unsigned)f2bf(f0)|((unsigned)f2bf(f1)<<16);
  v.y=(unsigned)f2bf(f2v)|((unsigned)f2bf(f3)<<16);
  xs[(size_t)n*8+l]=v;
}

// ---------------- aggregation body: out[d] = dinv[d]*(in[d] + sum in[src]) ----------------
// bf16 input rows of GROUP uint2 packs (4 dims/lane); output f32 float4 or bf16 uint2 rows.
template<int GROUP,bool BR,bool OUTBF>
DEV void agg_body(const uint2* __restrict__ xs, const int* __restrict__ col,
    const int* __restrict__ offs, const int* __restrict__ deg, const float* __restrict__ dinv,
    const float* __restrict__ bias, void* __restrict__ out, int M){
  int gid=blockIdx.x*256+threadIdx.x;
  int node=gid/GROUP, lane=gid%GROUP;
  if(node>=M) return;
  float a0,a1,a2,a3;
  {
    uint2 v=xs[(size_t)node*GROUP+lane];
    float2 p=bfu2f2(v.x), q=bfu2f2(v.y);
    a0=p.x; a1=p.y; a2=q.x; a3=q.y;
  }
  int e0=offs[node], d=deg[node];
  int i=0;
  for(;i+8<=d;i+=8){
    int s[8]; uint2 w[8];
    #pragma unroll
    for(int q=0;q<8;q++) s[q]=col[e0+i+q];
    #pragma unroll
    for(int q=0;q<8;q++) w[q]=xs[(size_t)s[q]*GROUP+lane];
    #pragma unroll
    for(int q=0;q<8;q++){
      float2 p=bfu2f2(w[q].x); a0+=p.x; a1+=p.y;
      p=bfu2f2(w[q].y); a2+=p.x; a3+=p.y;
    }
  }
  for(;i+4<=d;i+=4){
    int s[4]; uint2 w[4];
    #pragma unroll
    for(int q=0;q<4;q++) s[q]=col[e0+i+q];
    #pragma unroll
    for(int q=0;q<4;q++) w[q]=xs[(size_t)s[q]*GROUP+lane];
    #pragma unroll
    for(int q=0;q<4;q++){
      float2 p=bfu2f2(w[q].x); a0+=p.x; a1+=p.y;
      p=bfu2f2(w[q].y); a2+=p.x; a3+=p.y;
    }
  }
  for(;i<d;i++){
    uint2 w=xs[(size_t)col[e0+i]*GROUP+lane];
    float2 p=bfu2f2(w.x); a0+=p.x; a1+=p.y;
    p=bfu2f2(w.y); a2+=p.x; a3+=p.y;
  }
  float dv=dinv[node];
  a0*=dv; a1*=dv; a2*=dv; a3*=dv;
  if constexpr(BR){
    a0=fmaxf(a0+bias[4*lane  ],0.f);
    a1=fmaxf(a1+bias[4*lane+1],0.f);
    a2=fmaxf(a2+bias[4*lane+2],0.f);
    a3=fmaxf(a3+bias[4*lane+3],0.f);
  }
  if constexpr(OUTBF){
    uint2 v;
    v.x=(unsigned)f2bf(a0)|((unsigned)f2bf(a1)<<16);
    v.y=(unsigned)f2bf(a2)|((unsigned)f2bf(a3)<<16);
    ((uint2*)out)[(size_t)node*GROUP+lane]=v;
  } else {
    ((float4*)out)[(size_t)node*GROUP+lane]=make_float4(a0,a1,a2,a3);
  }
}

__global__ __launch_bounds__(256) void agg1_kernel(const uint2* xs, const int* col, const int* offs,
    const int* deg, const float* dinv, uint2* out, int M){
  agg_body<8,false,true>(xs,col,offs,deg,dinv,nullptr,out,M);
}
__global__ __launch_bounds__(256) void agg2_kernel(const uint2* xs, const int* col, const int* offs,
    const int* deg, const float* dinv, uint2* out, int M){
  agg_body<16,false,true>(xs,col,offs,deg,dinv,nullptr,out,M);
}
__global__ __launch_bounds__(256) void agg3_kernel(const uint2* xs, const int* col, const int* offs,
    const int* deg, const float* dinv, const float* bias, float4* out, int M){
  agg_body<16,true,false>(xs,col,offs,deg,dinv,bias,out,M);
}

// ---------------- W prep: split f32 W[K][N] (rows>=RK zero) into frag-ready bf16 hi/lo ----------------
// Layout: idx = ((nt*KS+ks)*64 + lane)*8 + j ; elem = W[ks*32+(lane>>4)*8+j][nt*16+(lane&15)]
__global__ __launch_bounds__(256) void wprep_kernel(const float* __restrict__ W,
    unsigned short* __restrict__ Warr, int KS, int RK, int N, int KN){
  int idx=blockIdx.x*256+threadIdx.x;
  if(idx>=KN) return;
  int j=idx&7, l=(idx>>3)&63, t=idx>>9;
  int ks=t%KS, nt=t/KS;
  int k=ks*32+((l>>4)<<3)+j;
  int c=nt*16+(l&15);
  float w=(k<RK)?W[(size_t)k*N+c]:0.f;
  unsigned short hi=f2bf(w);
  unsigned short lo=f2bf(w-bf2f(hi));
  Warr[idx]=hi;
  Warr[KN+idx]=lo;
}

// ---------------- MFMA GEMM (no LDS): Out[M,N]=epi(Xbf16[M,K] @ (Whi+Wlo)) ----------------
// A-frag: row=lane&15, k=ks*32+(lane>>4)*8+j (16B contiguous). B-frag from Warr.
// C/D: col=lane&15, row=(lane>>4)*4+reg.
template<int K,int NT,bool BR,bool DV>
DEV void mfma_gemm_body(const unsigned short* __restrict__ X, const unsigned short* __restrict__ Warr,
    const float* __restrict__ bias, const float* __restrict__ dinv, unsigned short* __restrict__ Out, int M){
  constexpr int KS=K/32;
  constexpr int N=NT*16;
  constexpr int KN=K*N;
  int tid=threadIdx.x;
  int lane=tid&63, wave=tid>>6;
  int rowbase=blockIdx.x*64+wave*16;
  int r=rowbase+(lane&15);
  int rc=min(r,M-1);
  const short* Xr=(const short*)(X+(size_t)rc*K+((lane>>4)<<3));
  short8 af[KS];
  #pragma unroll
  for(int ks=0;ks<KS;ks++) af[ks]=*(const short8*)(Xr+ks*32);
  const short* wp=(const short*)Warr+lane*8;
  int colv=lane&15;
  #pragma unroll
  for(int nt=0;nt<NT;nt++){
    f32x4 acc={0.f,0.f,0.f,0.f};
    const short* wnt=wp+nt*KS*512;
    #pragma unroll
    for(int ks=0;ks<KS;ks++){
      short8 bh=*(const short8*)(wnt+ks*512);
      short8 bl=*(const short8*)(wnt+KN+ks*512);
      acc=__builtin_amdgcn_mfma_f32_16x16x32_bf16(af[ks],bh,acc,0,0,0);
      acc=__builtin_amdgcn_mfma_f32_16x16x32_bf16(af[ks],bl,acc,0,0,0);
    }
    int c=nt*16+colv;
    float bv=0.f;
    if constexpr(BR) bv=bias[c];
    #pragma unroll
    for(int reg=0;reg<4;reg++){
      int row=rowbase+((lane>>4)<<2)+reg;
      if(row<M){
        float v=acc[reg];
        if constexpr(BR) v=fmaxf(v+bv,0.f);
        if constexpr(DV) v*=dinv[row];
        Out[(size_t)row*N+c]=f2bf(v);
      }
    }
  }
}

__global__ __launch_bounds__(256) void gemm1m_kernel(const unsigned short* X, const unsigned short* Warr,
    const float* bias, const float* dinv, unsigned short* Out, int M){
  mfma_gemm_body<32,4,true,true>(X,Warr,bias,dinv,Out,M);
}
__global__ __launch_bounds__(256) void gemm2m_kernel(const unsigned short* X, const unsigned short* Warr,
    const float* bias, unsigned short* Out, int M){
  mfma_gemm_body<64,8,true,false>(X,Warr,bias,nullptr,Out,M);
}
__global__ __launch_bounds__(256) void gemm3m_kernel(const unsigned short* X, const unsigned short* Warr,
    const float* dinv, unsigned short* Out, int M){
  mfma_gemm_body<128,4,false,true>(X,Warr,nullptr,dinv,Out,M);
}

// ---------------- fused MLP head: out = (relu(h@Wl1+bl1))@Wl2 + bl2 ----------------
__global__ __launch_bounds__(256) void mlp_kernel(const float* __restrict__ h, const float* __restrict__ W1,
    const float* __restrict__ b1, const float* __restrict__ W2, const float* __restrict__ b2,
    float* __restrict__ out, int M){
  __shared__ float W1s[64*20];
  __shared__ float b1s[20];
  __shared__ float W2s[20];
  __shared__ float b2s;
  int tid=threadIdx.x;
  for(int i=tid;i<1280;i+=256) W1s[i]=W1[i];
  if(tid<20){ b1s[tid]=b1[tid]; W2s[tid]=W2[tid]; }
  if(tid==0) b2s=b2[0];
  __syncthreads();
  int n=blockIdx.x*256+tid;
  if(n>=M) return;
  float acc[20];
  #pragma unroll
  for(int j=0;j<20;j++) acc[j]=b1s[j];
  const float4* hp=(const float4*)(h+(size_t)n*64);
  for(int k4=0;k4<16;k4++){
    float4 hv=hp[k4];
    #pragma unroll
    for(int j=0;j<20;j++){
      acc[j]=fmaf(hv.x,W1s[(k4*4+0)*20+j],acc[j]);
      acc[j]=fmaf(hv.y,W1s[(k4*4+1)*20+j],acc[j]);
      acc[j]=fmaf(hv.z,W1s[(k4*4+2)*20+j],acc[j]);
      acc[j]=fmaf(hv.w,W1s[(k4*4+3)*20+j],acc[j]);
    }
  }
  float r=b2s;
  #pragma unroll
  for(int j=0;j<20;j++) r+=fmaxf(acc[j],0.f)*W2s[j];
  out[n]=r;
}

extern "C" void kernel_launch(void* const* d_in, const int* in_sizes, int n_in,
                              void* d_out, int out_size, void* d_ws, size_t ws_size,
                              hipStream_t stream){
  const float* x  =(const float*)d_in[0];
  const int*   ei =(const int*)  d_in[1];
  const float* W1 =(const float*)d_in[2];
  const float* b1 =(const float*)d_in[3];
  const float* W2 =(const float*)d_in[4];
  const float* b2 =(const float*)d_in[5];
  const float* W3 =(const float*)d_in[6];
  const float* b3 =(const float*)d_in[7];
  const float* Wl1=(const float*)d_in[8];
  const float* bl1=(const float*)d_in[9];
  const float* Wl2=(const float*)d_in[10];
  const float* bl2=(const float*)d_in[11];
  const int M=in_sizes[0]/21;
  const int E=in_sizes[1]/2;
  const int* srcp=ei;
  const int* dstp=ei+(size_t)E;
  const int NB=(M+CB_NODES-1)/CB_NODES;   // coarse bins (<=256 for M<=131072)

  char* ws=(char*)d_ws;
  size_t off=0;
  auto alloc=[&](size_t bytes)->void*{
    off=(off+255)&~(size_t)255;
    void* p=ws+off; off+=bytes; return p;
  };
  int*   offs   =(int*)  alloc((size_t)M*4);
  int*   deg    =(int*)  alloc((size_t)M*4);
  float* dinv   =(float*)alloc((size_t)M*4);
  int*   bcnt   =(int*)  alloc(256*4);
  int*   binoffs=(int*)  alloc(257*4);
  int*   bincur =(int*)  alloc(256*4);
  unsigned short* W1arr=(unsigned short*)alloc(2*32*64*2);    // hi+lo
  unsigned short* W2arr=(unsigned short*)alloc(2*64*128*2);   // hi+lo
  unsigned short* W3arr=(unsigned short*)alloc(2*128*64*2);   // hi+lo
  int*   col    =(int*)  alloc((size_t)E*4);
  // four reusable 256B-per-node slots
  float* A=(float*)alloc((size_t)M*256);   // (alias: uint tmp[E]) xs0 bf16[M,32] -> h2 bf16[M,128]
  float* B=(float*)alloc((size_t)M*256);   // Y1 bf16[M,32] -> ts bf16[M,64]
  float* C=(float*)alloc((size_t)M*256);   // xs1 bf16[M,64] -> h3 f32[M,64]
  float* D=(float*)alloc((size_t)M*256);   // Y2 bf16[M,64]
  unsigned* tmp=(unsigned*)A;              // E*4 bytes <= M*256 bytes
  (void)ws_size;(void)n_in;(void)out_size;

  hipMemsetAsync(bcnt,0,256*4,stream);
  coarsehist_kernel<<<512,256,0,stream>>>(dstp,bcnt,E,NB);
  binscan_kernel<<<1,256,0,stream>>>(bcnt,binoffs,bincur,NB,E);
  chunkscatter_kernel<<<(E+CHUNK-1)/CHUNK,256,0,stream>>>(srcp,dstp,bincur,tmp,E,NB);
  binsort_kernel<<<NB,256,0,stream>>>(tmp,binoffs,offs,deg,dinv,col,M);
  wprep_kernel<<<(32*64+255)/256,256,0,stream>>>(W1,W1arr,1,21,64,32*64);
  wprep_kernel<<<(64*128+255)/256,256,0,stream>>>(W2,W2arr,2,64,128,64*128);
  wprep_kernel<<<(128*64+255)/256,256,0,stream>>>(W3,W3arr,4,128,64,128*64);

  // layer 1: xs0 bf16[M,32]; aggregate (GROUP=8, out bf16 Y1); MFMA GEMM 21->64 (bias+relu+dinv, bf16 xs1)
  scale_kernel<<<(M*8+255)/256,256,0,stream>>>(x,dinv,(uint2*)A,M);
  agg1_kernel<<<(M*8+255)/256,256,0,stream>>>((const uint2*)A,col,offs,deg,dinv,(uint2*)B,M);
  gemm1m_kernel<<<(M+63)/64,256,0,stream>>>((const unsigned short*)B,W1arr,b1,dinv,(unsigned short*)C,M);
  // layer 2: aggregate bf16 (GROUP=16, out bf16 Y2); MFMA GEMM 64->128 (bias+relu), h2 bf16
  agg2_kernel<<<(M*16+255)/256,256,0,stream>>>((const uint2*)C,col,offs,deg,dinv,(uint2*)D,M);
  gemm2m_kernel<<<(M+63)/64,256,0,stream>>>((const unsigned short*)D,W2arr,b2,(unsigned short*)A,M);
  // layer 3: MFMA GEMM 128->64 (dinv, out bf16 ts), then aggregate (bias+relu epilogue)
  gemm3m_kernel<<<(M+63)/64,256,0,stream>>>((const unsigned short*)A,W3arr,dinv,(unsigned short*)B,M);
  agg3_kernel<<<(M*16+255)/256,256,0,stream>>>((const uint2*)B,col,offs,deg,dinv,b3,(float4*)C,M);
  // MLP head
  mlp_kernel<<<(M+255)/256,256,0,stream>>>(C,Wl1,bl1,Wl2,bl2,(float*)d_out,M);
}